// Round 4
// baseline (2140.775 us; speedup 1.0000x reference)
//
#include <hip/hip_runtime.h>

// ---------------- problem constants ----------------
#define BB 16
#define SS 100
#define HH 400      // hidden per direction
#define H2 800
#define G4 1600     // 4*H gate rows
#define DIN0 150    // WE+PE

// ---------------- workspace layout (float offsets) ----------------
#define OFF_X0   0ULL          // 240,000
#define OFF_GF   240000ULL     // 2,560,000 (g0f / g1f / ua)
#define OFF_GB   2800000ULL    // 2,560,000 (g0b / g1b / wa)
#define OFF_H1   5360000ULL    // 1,280,000
#define OFF_OUT2 6640000ULL    // 1,280,000
#define OFF_SC   7920000ULL    // 158,400
#define OFF_NLL  8078400ULL    // 1,600
#define OFF_CNT  8080000ULL    // 1,600 ints
#define OFF_EXH  8081600ULL    // u16 exchange planes start (128B aligned)
#define EX_U16_PER_PLANE 1331200ULL   // 2 dir * 100 steps * 13 kt * 64 * 8

typedef _Float16 f16x8 __attribute__((ext_vector_type(8)));
typedef float    f32x4 __attribute__((ext_vector_type(4)));

// ---------------- embedding ----------------
__global__ __launch_bounds__(256) void embed_kernel(
    const int* __restrict__ tok, const int* __restrict__ pos,
    const float* __restrict__ wW, const float* __restrict__ pW,
    float* __restrict__ x0)
{
    int idx = blockIdx.x * 256 + threadIdx.x;
    if (idx >= BB * SS * DIN0) return;
    int n = idx / DIN0, d = idx % DIN0;
    x0[idx] = (d < 100) ? wW[tok[n] * 100 + d] : pW[pos[n] * 50 + (d - 100)];
}

// ---------------- generic NT GEMM (fp32 VALU, used for K=150 only) ----------------
__global__ __launch_bounds__(256) void gemm_nt_bias(
    const float* __restrict__ A, const float* __restrict__ W,
    const float* __restrict__ bias, float* __restrict__ C,
    int N, int K, int R)
{
    __shared__ __attribute__((aligned(16))) float As[16][68];
    __shared__ __attribute__((aligned(16))) float Ws[16][68];
    int tid = threadIdx.x;
    int tx = tid & 15, ty = tid >> 4;
    int row0 = blockIdx.y * 64, col0 = blockIdx.x * 64;
    float acc[4][4];
#pragma unroll
    for (int i = 0; i < 4; i++)
#pragma unroll
        for (int j = 0; j < 4; j++) acc[i][j] = 0.f;

    int ktiles = (K + 15) >> 4;
    for (int kt = 0; kt < ktiles; kt++) {
        int kb = kt << 4;
#pragma unroll
        for (int e = 0; e < 4; e++) {
            int i = tid + (e << 8);
            int r = i >> 4, kk = i & 15;
            int gk = kb + kk;
            As[kk][r] = (row0 + r < N && gk < K) ? A[(size_t)(row0 + r) * K + gk] : 0.f;
            Ws[kk][r] = (col0 + r < R && gk < K) ? W[(size_t)(col0 + r) * K + gk] : 0.f;
        }
        __syncthreads();
#pragma unroll
        for (int kk = 0; kk < 16; kk++) {
            float4 av = *(const float4*)&As[kk][ty * 4];
            float4 wv = *(const float4*)&Ws[kk][tx * 4];
            float a[4] = {av.x, av.y, av.z, av.w};
            float w[4] = {wv.x, wv.y, wv.z, wv.w};
#pragma unroll
            for (int i = 0; i < 4; i++)
#pragma unroll
                for (int j = 0; j < 4; j++) acc[i][j] = fmaf(a[i], w[j], acc[i][j]);
        }
        __syncthreads();
    }
#pragma unroll
    for (int i = 0; i < 4; i++) {
        int gr = row0 + ty * 4 + i;
        if (gr >= N) continue;
        int gc = col0 + tx * 4;
        if (gc >= R) continue;
        float4 o;
        o.x = acc[i][0] + (bias ? bias[gc + 0] : 0.f);
        o.y = acc[i][1] + (bias ? bias[gc + 1] : 0.f);
        o.z = acc[i][2] + (bias ? bias[gc + 2] : 0.f);
        o.w = acc[i][3] + (bias ? bias[gc + 3] : 0.f);
        *(float4*)&C[(size_t)gr * R + gc] = o;
    }
}

// ---------------- f32 -> f16 hi/lo pair conversion (8 elems, scalar casts) ----------------
// w = hi + lo/2048 to ~2^-22 relative; lo pre-scaled x2048 stays in f16 normal range.
static __device__ __forceinline__ void cvt_pair8(float4 a, float4 b,
                                                 f16x8& hi, f16x8& lo)
{
    float v[8] = {a.x, a.y, a.z, a.w, b.x, b.y, b.z, b.w};
#pragma unroll
    for (int i = 0; i < 8; i++) {
        _Float16 h = (_Float16)v[i];
        hi[i] = h;
        lo[i] = (_Float16)((v[i] - (float)h) * 2048.f);
    }
}

// ---------------- MFMA NT GEMM (fp32 in/out, f16 hi/lo 3-plane, K % 32 == 0) ----------------
// grid: (ceil(R/64), N/64), 256 threads = 4 waves. Wave w: rows rs..rs+15, cols n0..n0+63.
// Fragment layout identical to the verified lstm kernel: both operands use lane&15 as
// the row/col index and lane>>4 as the k-chunk; D: col = lane&15, row = (lane>>4)*4+q.
__global__ __launch_bounds__(256) void gemm_nt_mfma(
    const float* __restrict__ A, const float* __restrict__ W,
    const float* __restrict__ bias, float* __restrict__ C,
    int N, int K, int R)
{
    int tid = threadIdx.x;
    int wv = tid >> 6, l = tid & 63;
    int lm = l & 15, lk = l >> 4;
    int rs = blockIdx.x * 64 + wv * 16;
    if (rs >= R) return;                        // uniform per-wave; no __syncthreads in kernel
    int n0 = blockIdx.y * 64;

    const float* wrow = W + (size_t)(rs + lm) * K + lk * 8;
    const float* arow = A + (size_t)(n0 + lm) * K + lk * 8;

    f32x4 accH[4], accX[4];
#pragma unroll
    for (int ct = 0; ct < 4; ct++) {
        accH[ct] = {0.f, 0.f, 0.f, 0.f};
        accX[ct] = {0.f, 0.f, 0.f, 0.f};
    }

    int ksteps = K >> 5;
    for (int kt = 0; kt < ksteps; kt++) {
        int kb = kt << 5;
        float4 wlo4 = *(const float4*)(wrow + kb);
        float4 whi4 = *(const float4*)(wrow + kb + 4);
        f16x8 wh, wl;
        cvt_pair8(wlo4, whi4, wh, wl);
#pragma unroll
        for (int ct = 0; ct < 4; ct++) {
            const float* ap = arow + (size_t)(ct * 16) * K + kb;
            float4 aa = *(const float4*)ap;
            float4 ab = *(const float4*)(ap + 4);
            f16x8 ah, al;
            cvt_pair8(aa, ab, ah, al);
            accH[ct] = __builtin_amdgcn_mfma_f32_16x16x32_f16(wh, ah, accH[ct], 0, 0, 0);
            accX[ct] = __builtin_amdgcn_mfma_f32_16x16x32_f16(wh, al, accX[ct], 0, 0, 0);
            accX[ct] = __builtin_amdgcn_mfma_f32_16x16x32_f16(wl, ah, accX[ct], 0, 0, 0);
        }
    }

    float4 bv = *(const float4*)&bias[rs + lk * 4];
#pragma unroll
    for (int ct = 0; ct < 4; ct++) {
        f32x4 v = accH[ct] + accX[ct] * (1.f / 2048.f);
        float4 o;
        o.x = v[0] + bv.x; o.y = v[1] + bv.y; o.z = v[2] + bv.z; o.w = v[3] + bv.w;
        *(float4*)&C[(size_t)(n0 + ct * 16 + lm) * R + rs + lk * 4] = o;
    }
}

// ---------------- LSTM recurrence: MFMA f16 hi/lo split, counter step barrier ----------------
// (round-1 verified version, 455 us/dispatch)
__global__ __launch_bounds__(64, 1) void lstm_layer_kernel(
    const float* __restrict__ Gf, const float* __restrict__ Gb,
    const float* __restrict__ Wf, const float* __restrict__ Wb,
    float* __restrict__ hbuf,          // [B][S][800] fp32 for downstream kernels
    int* __restrict__ cnt,             // [2][100][4] step counters
    unsigned short* __restrict__ exhi, // f16 hi plane, frag layout [dir][s][kt][64][8]
    unsigned short* __restrict__ exlo) // f16 lo plane (x2048)
{
    const int dir = blockIdx.x / 100;
    const int wg  = blockIdx.x % 100;
    const int j0  = wg * 4;
    const float* __restrict__ G = dir ? Gb : Gf;
    const float* __restrict__ W = dir ? Wb : Wf;

    const int l   = threadIdx.x;   // 0..63
    const int b   = l & 15;
    const int hi4 = l >> 4;

    __shared__ __attribute__((aligned(16))) unsigned short ahi[13 * 64 * 8];
    __shared__ __attribute__((aligned(16))) unsigned short alo[13 * 64 * 8];
    __shared__ float gl[16 * 17];

    // ---- one-time: weights -> f16 hi/lo A-fragments in LDS ----
    {
        const int m = b;
        const int g = m >> 2, jj = m & 3;
        const float* wrow = W + (size_t)(g * HH + j0 + jj) * HH;
        for (int kt = 0; kt < 13; kt++) {
            for (int e = 0; e < 8; e++) {
                int k = kt * 32 + hi4 * 8 + e;
                float w = (k < HH) ? wrow[k] : 0.f;
                _Float16 wh = (_Float16)w;
                _Float16 wl = (_Float16)((w - (float)wh) * 2048.f);
                ahi[(kt * 64 + l) * 8 + e] = __builtin_bit_cast(unsigned short, wh);
                alo[(kt * 64 + l) * 8 + e] = __builtin_bit_cast(unsigned short, wl);
            }
        }
    }
    __syncthreads();

    float c_reg = 0.f;
    unsigned short* exh_d = exhi + (size_t)dir * 100 * 13 * 512;
    unsigned short* exl_d = exlo + (size_t)dir * 100 * 13 * 512;

    for (int s = 0; s < SS; s++) {
        const int time = dir ? (SS - 1 - s) : s;
        f32x4 gpre = *(const f32x4*)&G[(size_t)(b * SS + time) * G4 + hi4 * HH + j0];

        f32x4 acc;
        if (s > 0) {
            int* c4 = cnt + (dir * SS + (s - 1)) * 4;
            if (l == 0) {
                for (int guard = 0; guard < (1 << 22); guard++) {
                    int sum = 0;
#pragma unroll
                    for (int q = 0; q < 4; q++)
                        sum += __hip_atomic_load(c4 + q, __ATOMIC_RELAXED, __HIP_MEMORY_SCOPE_AGENT);
                    if (sum >= 100) break;
                    __builtin_amdgcn_s_sleep(1);
                }
            }
            __syncthreads();
            asm volatile("" ::: "memory");   // no load hoisting above the poll

            const f16x8* __restrict__ pbh = (const f16x8*)(exh_d + (size_t)(s - 1) * 13 * 512);
            const f16x8* __restrict__ pbl = (const f16x8*)(exl_d + (size_t)(s - 1) * 13 * 512);
            f16x8 bh[13], bl[13];
#pragma unroll
            for (int kt = 0; kt < 13; kt++) {
                bh[kt] = pbh[kt * 64 + l];
                bl[kt] = pbl[kt * 64 + l];
            }
            f32x4 aHH = gpre;
            f32x4 aHL = {0.f, 0.f, 0.f, 0.f};
            f32x4 aLH = {0.f, 0.f, 0.f, 0.f};
#pragma unroll
            for (int kt = 0; kt < 13; kt++) {
                f16x8 wh = *(const f16x8*)&ahi[(kt * 64 + l) * 8];
                f16x8 wl = *(const f16x8*)&alo[(kt * 64 + l) * 8];
                aHH = __builtin_amdgcn_mfma_f32_16x16x32_f16(wh, bh[kt], aHH, 0, 0, 0);
                aHL = __builtin_amdgcn_mfma_f32_16x16x32_f16(wh, bl[kt], aHL, 0, 0, 0);
                aLH = __builtin_amdgcn_mfma_f32_16x16x32_f16(wl, bh[kt], aLH, 0, 0, 0);
            }
            acc = aHH + (aHL + aLH) * (1.f / 2048.f);
        } else {
            acc = gpre;   // h(-1) = 0
        }

#pragma unroll
        for (int q = 0; q < 4; q++) gl[(4 * hi4 + q) * 17 + b] = acc[q];
        __syncthreads();

        const int jj = hi4;
        float gi = gl[( 0 + jj) * 17 + b];
        float gf = gl[( 4 + jj) * 17 + b];
        float gg = gl[( 8 + jj) * 17 + b];
        float go = gl[(12 + jj) * 17 + b];
        __syncthreads();

        float si = 1.f / (1.f + expf(-gi));
        float sf = 1.f / (1.f + expf(-gf));
        float tg = tanhf(gg);
        float so = 1.f / (1.f + expf(-go));
        float c  = sf * c_reg + si * tg;
        c_reg = c;
        float h  = so * tanhf(c);

        hbuf[(size_t)(b * SS + time) * H2 + dir * HH + j0 + jj] = h;

        if (s < SS - 1) {
            _Float16 hh = (_Float16)h;
            _Float16 hl = (_Float16)((h - (float)hh) * 2048.f);
            unsigned uh = __builtin_bit_cast(unsigned short, hh);
            unsigned ul = __builtin_bit_cast(unsigned short, hl);
            unsigned ph = uh | (((unsigned)__shfl_down((int)uh, 16)) << 16);
            unsigned pl = ul | (((unsigned)__shfl_down((int)ul, 16)) << 16);
            if ((jj & 1) == 0) {
                int k0 = j0 + jj;
                int kt = k0 >> 5, ko = k0 & 31;
                int lg = ko >> 3, e = ko & 7;
                size_t u16idx = ((size_t)(s * 13 + kt) * 64 + (lg * 16 + b)) * 8 + e;
                __hip_atomic_store((unsigned*)(exh_d + u16idx), ph,
                                   __ATOMIC_RELAXED, __HIP_MEMORY_SCOPE_AGENT);
                __hip_atomic_store((unsigned*)(exl_d + u16idx), pl,
                                   __ATOMIC_RELAXED, __HIP_MEMORY_SCOPE_AGENT);
            }
            asm volatile("s_waitcnt vmcnt(0)" ::: "memory");
            if (l == 0)
                __hip_atomic_fetch_add(cnt + (dir * SS + s) * 4 + (wg & 3), 1,
                                       __ATOMIC_RELEASE, __HIP_MEMORY_SCOPE_AGENT);
        }
    }
}

// ---------------- attention scores ----------------
#define ITILE 11
__global__ __launch_bounds__(256) void attn_scores_kernel(
    const float* __restrict__ ua, const float* __restrict__ wa,
    const float* __restrict__ va, float* __restrict__ scores)
{
    int b  = blockIdx.x / 9;
    int i0 = (blockIdx.x % 9) * ITILE;
    int tid = threadIdx.x;
    __shared__ float ua_t[100][101];
    __shared__ float wa_t[ITILE][102];
    __shared__ float sacc[ITILE][101];
    __shared__ float va_t[100];

    for (int p = tid; p < ITILE * 101; p += 256) ((float*)sacc)[p] = 0.f;

    for (int ht = 0; ht < 8; ht++) {
        int h0 = ht * 100;
        __syncthreads();
        for (int p = tid; p < 100 * 100; p += 256) {
            int j = p / 100, hh = p % 100;
            ua_t[j][hh] = ua[(size_t)(b * SS + j) * H2 + h0 + hh];
        }
        for (int p = tid; p < ITILE * 100; p += 256) {
            int il = p / 100, hh = p % 100;
            wa_t[il][hh] = wa[(size_t)(b * SS + i0 + il + 1) * H2 + h0 + hh];
        }
        if (tid < 100) va_t[tid] = va[h0 + tid];
        __syncthreads();
        for (int p = tid; p < ITILE * 100; p += 256) {
            int il = p / 100, j = p % 100;
            float acc = 0.f;
#pragma unroll 4
            for (int hh = 0; hh < 100; hh++) {
                float x = ua_t[j][hh] + wa_t[il][hh];
                float z = __expf(2.f * x);
                float th = 1.f - 2.f * __builtin_amdgcn_rcpf(z + 1.f);
                acc = fmaf(th, va_t[hh], acc);
            }
            sacc[il][j] += acc;
        }
    }
    __syncthreads();
    for (int p = tid; p < ITILE * 100; p += 256) {
        int il = p / 100, j = p % 100;
        scores[(size_t)(b * 99 + i0 + il) * 100 + j] = sacc[il][j];
    }
}

// ---------------- softmax / table / preds / nll per (b,i) row ----------------
__global__ __launch_bounds__(128) void attn_softmax_kernel(
    const float* __restrict__ scores, const float* __restrict__ out2,
    const int* __restrict__ head, float* __restrict__ outb,
    float* __restrict__ nll)
{
    int bi = blockIdx.x;           // b*99 + i
    int b = bi / 99, i = bi % 99;
    int j = threadIdx.x;
    __shared__ float sv[128];
    __shared__ int   si[128];
    __shared__ float red[128];

    float h_t = out2[(size_t)(b * SS + i + 1) * H2];
    float sj = -1e30f;
    if (j < 100) {
        sj = scores[(size_t)bi * 100 + j];
        float h_j = out2[(size_t)(b * SS + j) * H2];
        if (h_j == h_t) sj = -10000.0f;
    }
    sv[j] = sj; si[j] = j;
    __syncthreads();
    for (int off = 64; off >= 1; off >>= 1) {
        if (j < off) {
            float o = sv[j + off]; int oi = si[j + off];
            if (o > sv[j] || (o == sv[j] && oi < si[j])) { sv[j] = o; si[j] = oi; }
        }
        __syncthreads();
    }
    float m = sv[0]; int amax = si[0];
    __syncthreads();
    float e = (j < 100) ? __expf(sj - m) : 0.f;
    red[j] = e;
    __syncthreads();
    for (int off = 64; off >= 1; off >>= 1) {
        if (j < off) red[j] += red[j + off];
        __syncthreads();
    }
    float sum = red[0];
    float inv = 1.f / sum;
    if (j < 100) outb[1 + 1584 + (size_t)bi * 100 + j] = e * inv;
    if (j == 0) {
        outb[1 + bi] = (float)amax;
        int gold = head[b * SS + i + 1];
        bool valid = (gold != -1);
        int gc = gold < 0 ? 0 : (gold > 99 ? 99 : gold);
        float sgc = scores[(size_t)bi * 100 + gc];
        float hgc = out2[(size_t)(b * SS + gc) * H2];
        if (hgc == h_t) sgc = -10000.0f;
        nll[bi] = valid ? -(sgc - m - logf(sum)) : 0.f;
    }
}

// ---------------- final loss reduction ----------------
__global__ __launch_bounds__(128) void loss_kernel(
    const float* __restrict__ nll, const int* __restrict__ head,
    float* __restrict__ outb)
{
    __shared__ float red[128];
    int tid = threadIdx.x;
    float contrib = 0.f;
    if (tid < 99) {
        int i = tid;
        float tot = 0.f; int cv = 0;
        for (int b = 0; b < BB; b++) {
            tot += nll[b * 99 + i];
            cv += (head[b * SS + i + 1] != -1) ? 1 : 0;
        }
        int denom = cv > 0 ? cv : 1;
        contrib = tot / (float)denom;
    }
    red[tid] = contrib;
    __syncthreads();
    for (int off = 64; off >= 1; off >>= 1) {
        if (tid < off) red[tid] += red[tid + off];
        __syncthreads();
    }
    if (tid == 0) outb[0] = red[0];
}

// ---------------- launch ----------------
extern "C" void kernel_launch(void* const* d_in, const int* in_sizes, int n_in,
                              void* d_out, int out_size, void* d_ws, size_t ws_size,
                              hipStream_t stream) {
    const int*   tok     = (const int*)d_in[0];
    const int*   pos     = (const int*)d_in[1];
    const int*   head    = (const int*)d_in[2];
    const float* word_W  = (const float*)d_in[3];
    const float* pos_W   = (const float*)d_in[4];
    const float* l0f_Wih = (const float*)d_in[5];
    const float* l0f_Whh = (const float*)d_in[6];
    const float* l0f_b   = (const float*)d_in[7];
    const float* l0b_Wih = (const float*)d_in[8];
    const float* l0b_Whh = (const float*)d_in[9];
    const float* l0b_b   = (const float*)d_in[10];
    const float* l1f_Wih = (const float*)d_in[11];
    const float* l1f_Whh = (const float*)d_in[12];
    const float* l1f_b   = (const float*)d_in[13];
    const float* l1b_Wih = (const float*)d_in[14];
    const float* l1b_Whh = (const float*)d_in[15];
    const float* l1b_b   = (const float*)d_in[16];
    const float* ua_W    = (const float*)d_in[17];
    const float* ua_b    = (const float*)d_in[18];
    const float* wa_W    = (const float*)d_in[19];
    const float* wa_b    = (const float*)d_in[20];
    const float* va_W    = (const float*)d_in[21];

    float* ws   = (float*)d_ws;
    float* x0   = ws + OFF_X0;
    float* gf   = ws + OFF_GF;   // also g1f, then ua
    float* gb   = ws + OFF_GB;   // also g1b, then wa
    float* h1   = ws + OFF_H1;
    float* out2 = ws + OFF_OUT2;
    float* sc   = ws + OFF_SC;
    float* nllb = ws + OFF_NLL;
    int*   cnt  = (int*)(ws + OFF_CNT);
    unsigned short* exhi = (unsigned short*)(ws + OFF_EXH);
    unsigned short* exlo = exhi + EX_U16_PER_PLANE;
    float* outf = (float*)d_out;

    hipMemsetAsync(cnt, 0, 1600 * sizeof(int), stream);
    // zero exchange planes (keeps padded-K tail zero so 0*tail can't make NaN)
    hipMemsetAsync(exhi, 0, 2 * EX_U16_PER_PLANE * sizeof(unsigned short), stream);

    embed_kernel<<<dim3((BB * SS * DIN0 + 255) / 256), 256, 0, stream>>>(
        tok, pos, word_W, pos_W, x0);

    // layer-0 input projections (K=150 -> fp32 VALU kernel)
    gemm_nt_bias<<<dim3(25, 25), 256, 0, stream>>>(x0, l0f_Wih, l0f_b, gf, 1600, DIN0, G4);
    gemm_nt_bias<<<dim3(25, 25), 256, 0, stream>>>(x0, l0b_Wih, l0b_b, gb, 1600, DIN0, G4);
    // layer-0 recurrence
    lstm_layer_kernel<<<dim3(200), 64, 0, stream>>>(
        gf, gb, l0f_Whh, l0b_Whh, h1, cnt, exhi, exlo);
    // layer-1 input projections (K=800 -> MFMA)
    gemm_nt_mfma<<<dim3(25, 25), 256, 0, stream>>>(h1, l1f_Wih, l1f_b, gf, 1600, H2, G4);
    gemm_nt_mfma<<<dim3(25, 25), 256, 0, stream>>>(h1, l1b_Wih, l1b_b, gb, 1600, H2, G4);
    // layer-1 recurrence
    lstm_layer_kernel<<<dim3(200), 64, 0, stream>>>(
        gf, gb, l1f_Whh, l1b_Whh, out2, cnt + 800, exhi, exlo);
    // attention projections (K=800 -> MFMA; R=800 -> 13 r-blocks, last half-idle)
    gemm_nt_mfma<<<dim3(13, 25), 256, 0, stream>>>(out2, ua_W, ua_b, gf, 1600, H2, H2);
    gemm_nt_mfma<<<dim3(13, 25), 256, 0, stream>>>(out2, wa_W, wa_b, gb, 1600, H2, H2);
    // scores, softmax/table/preds/nll, loss
    attn_scores_kernel<<<dim3(16 * 9), 256, 0, stream>>>(gf, gb, va_W, sc);
    attn_softmax_kernel<<<dim3(1584), 128, 0, stream>>>(sc, out2, head, outf, nllb);
    loss_kernel<<<dim3(1), 128, 0, stream>>>(nllb, head, outf);
}

// Round 5
// 1559.291 us; speedup vs baseline: 1.3729x; 1.3729x over previous
//
#include <hip/hip_runtime.h>

// ---------------- problem constants ----------------
#define BB 16
#define SS 100
#define HH 400      // hidden per direction
#define H2 800
#define G4 1600     // 4*H gate rows
#define DIN0 150    // WE+PE

// ---------------- workspace layout (float offsets) ----------------
#define OFF_X0   0ULL          // 240,000
#define OFF_GF   240000ULL     // 2,560,000 (g0f / g1f / ua)
#define OFF_GB   2800000ULL    // 2,560,000 (g0b / g1b / wa)
#define OFF_H1   5360000ULL    // 1,280,000
#define OFF_OUT2 6640000ULL    // 1,280,000
#define OFF_SC   7920000ULL    // 158,400
#define OFF_NLL  8078400ULL    // 1,600
#define OFF_CNT  8080000ULL    // 1,600 ints
#define OFF_EXH  8081600ULL    // u16 exchange planes start (128B aligned)
#define EX_U16_PER_PLANE 1331200ULL   // 2 dir * 100 steps * 13 kt * 64 * 8

typedef _Float16 f16x8 __attribute__((ext_vector_type(8)));
typedef float    f32x4 __attribute__((ext_vector_type(4)));

// ---------------- embedding ----------------
__global__ __launch_bounds__(256) void embed_kernel(
    const int* __restrict__ tok, const int* __restrict__ pos,
    const float* __restrict__ wW, const float* __restrict__ pW,
    float* __restrict__ x0)
{
    int idx = blockIdx.x * 256 + threadIdx.x;
    if (idx >= BB * SS * DIN0) return;
    int n = idx / DIN0, d = idx % DIN0;
    x0[idx] = (d < 100) ? wW[tok[n] * 100 + d] : pW[pos[n] * 50 + (d - 100)];
}

// ---------------- generic NT GEMM (fp32 VALU, used for K=150 only) ----------------
__global__ __launch_bounds__(256) void gemm_nt_bias(
    const float* __restrict__ A, const float* __restrict__ W,
    const float* __restrict__ bias, float* __restrict__ C,
    int N, int K, int R)
{
    __shared__ __attribute__((aligned(16))) float As[16][68];
    __shared__ __attribute__((aligned(16))) float Ws[16][68];
    int tid = threadIdx.x;
    int tx = tid & 15, ty = tid >> 4;
    int row0 = blockIdx.y * 64, col0 = blockIdx.x * 64;
    float acc[4][4];
#pragma unroll
    for (int i = 0; i < 4; i++)
#pragma unroll
        for (int j = 0; j < 4; j++) acc[i][j] = 0.f;

    int ktiles = (K + 15) >> 4;
    for (int kt = 0; kt < ktiles; kt++) {
        int kb = kt << 4;
#pragma unroll
        for (int e = 0; e < 4; e++) {
            int i = tid + (e << 8);
            int r = i >> 4, kk = i & 15;
            int gk = kb + kk;
            As[kk][r] = (row0 + r < N && gk < K) ? A[(size_t)(row0 + r) * K + gk] : 0.f;
            Ws[kk][r] = (col0 + r < R && gk < K) ? W[(size_t)(col0 + r) * K + gk] : 0.f;
        }
        __syncthreads();
#pragma unroll
        for (int kk = 0; kk < 16; kk++) {
            float4 av = *(const float4*)&As[kk][ty * 4];
            float4 wv = *(const float4*)&Ws[kk][tx * 4];
            float a[4] = {av.x, av.y, av.z, av.w};
            float w[4] = {wv.x, wv.y, wv.z, wv.w};
#pragma unroll
            for (int i = 0; i < 4; i++)
#pragma unroll
                for (int j = 0; j < 4; j++) acc[i][j] = fmaf(a[i], w[j], acc[i][j]);
        }
        __syncthreads();
    }
#pragma unroll
    for (int i = 0; i < 4; i++) {
        int gr = row0 + ty * 4 + i;
        if (gr >= N) continue;
        int gc = col0 + tx * 4;
        if (gc >= R) continue;
        float4 o;
        o.x = acc[i][0] + (bias ? bias[gc + 0] : 0.f);
        o.y = acc[i][1] + (bias ? bias[gc + 1] : 0.f);
        o.z = acc[i][2] + (bias ? bias[gc + 2] : 0.f);
        o.w = acc[i][3] + (bias ? bias[gc + 3] : 0.f);
        *(float4*)&C[(size_t)gr * R + gc] = o;
    }
}

// ---------------- f32 -> f16 hi/lo pair conversion (8 elems, scalar casts) ----------------
// w = hi + lo/2048 to ~2^-22 relative; lo pre-scaled x2048 stays in f16 normal range.
static __device__ __forceinline__ void cvt_pair8(float4 a, float4 b,
                                                 f16x8& hi, f16x8& lo)
{
    float v[8] = {a.x, a.y, a.z, a.w, b.x, b.y, b.z, b.w};
#pragma unroll
    for (int i = 0; i < 8; i++) {
        _Float16 h = (_Float16)v[i];
        hi[i] = h;
        lo[i] = (_Float16)((v[i] - (float)h) * 2048.f);
    }
}

// ---------------- MFMA NT GEMM (fp32 in/out, f16 hi/lo 3-plane, K % 32 == 0) ----------------
// grid: (ceil(R/64), N/64), 256 threads = 4 waves. Wave w: rows rs..rs+15, cols n0..n0+63.
// Fragment layout identical to the verified lstm kernel: both operands use lane&15 as
// the row/col index and lane>>4 as the k-chunk; D: col = lane&15, row = (lane>>4)*4+q.
__global__ __launch_bounds__(256) void gemm_nt_mfma(
    const float* __restrict__ A, const float* __restrict__ W,
    const float* __restrict__ bias, float* __restrict__ C,
    int N, int K, int R)
{
    int tid = threadIdx.x;
    int wv = tid >> 6, l = tid & 63;
    int lm = l & 15, lk = l >> 4;
    int rs = blockIdx.x * 64 + wv * 16;
    if (rs >= R) return;                        // uniform per-wave; no __syncthreads in kernel
    int n0 = blockIdx.y * 64;

    const float* wrow = W + (size_t)(rs + lm) * K + lk * 8;
    const float* arow = A + (size_t)(n0 + lm) * K + lk * 8;

    f32x4 accH[4], accX[4];
#pragma unroll
    for (int ct = 0; ct < 4; ct++) {
        accH[ct] = {0.f, 0.f, 0.f, 0.f};
        accX[ct] = {0.f, 0.f, 0.f, 0.f};
    }

    int ksteps = K >> 5;
    for (int kt = 0; kt < ksteps; kt++) {
        int kb = kt << 5;
        float4 wlo4 = *(const float4*)(wrow + kb);
        float4 whi4 = *(const float4*)(wrow + kb + 4);
        f16x8 wh, wl;
        cvt_pair8(wlo4, whi4, wh, wl);
#pragma unroll
        for (int ct = 0; ct < 4; ct++) {
            const float* ap = arow + (size_t)(ct * 16) * K + kb;
            float4 aa = *(const float4*)ap;
            float4 ab = *(const float4*)(ap + 4);
            f16x8 ah, al;
            cvt_pair8(aa, ab, ah, al);
            accH[ct] = __builtin_amdgcn_mfma_f32_16x16x32_f16(wh, ah, accH[ct], 0, 0, 0);
            accX[ct] = __builtin_amdgcn_mfma_f32_16x16x32_f16(wh, al, accX[ct], 0, 0, 0);
            accX[ct] = __builtin_amdgcn_mfma_f32_16x16x32_f16(wl, ah, accX[ct], 0, 0, 0);
        }
    }

    float4 bv = *(const float4*)&bias[rs + lk * 4];
#pragma unroll
    for (int ct = 0; ct < 4; ct++) {
        f32x4 v = accH[ct] + accX[ct] * (1.f / 2048.f);
        float4 o;
        o.x = v[0] + bv.x; o.y = v[1] + bv.y; o.z = v[2] + bv.z; o.w = v[3] + bv.w;
        *(float4*)&C[(size_t)(n0 + ct * 16 + lm) * R + rs + lk * 4] = o;
    }
}

// ---------------- LSTM recurrence: MFMA f16 hi/lo split, counter step barrier ----------------
// EXACT round-1 verified version (455 us/dispatch).
// Producer signal is RELAXED fetch_add: the preceding s_waitcnt vmcnt(0) already
// orders the LLC-scope h stores; a RELEASE RMW at agent scope adds an L2 writeback
// (buffer_wbl2) per step per WG -> +300 us/dispatch (measured round 4).
__global__ __launch_bounds__(64, 1) void lstm_layer_kernel(
    const float* __restrict__ Gf, const float* __restrict__ Gb,
    const float* __restrict__ Wf, const float* __restrict__ Wb,
    float* __restrict__ hbuf,          // [B][S][800] fp32 for downstream kernels
    int* __restrict__ cnt,             // [2][100][4] step counters
    unsigned short* __restrict__ exhi, // f16 hi plane, frag layout [dir][s][kt][64][8]
    unsigned short* __restrict__ exlo) // f16 lo plane (x2048)
{
    const int dir = blockIdx.x / 100;
    const int wg  = blockIdx.x % 100;
    const int j0  = wg * 4;
    const float* __restrict__ G = dir ? Gb : Gf;
    const float* __restrict__ W = dir ? Wb : Wf;

    const int l   = threadIdx.x;   // 0..63
    const int b   = l & 15;
    const int hi4 = l >> 4;

    __shared__ __attribute__((aligned(16))) unsigned short ahi[13 * 64 * 8];
    __shared__ __attribute__((aligned(16))) unsigned short alo[13 * 64 * 8];
    __shared__ float gl[16 * 17];

    // ---- one-time: weights -> f16 hi/lo A-fragments in LDS ----
    {
        const int m = b;
        const int g = m >> 2, jj = m & 3;
        const float* wrow = W + (size_t)(g * HH + j0 + jj) * HH;
        for (int kt = 0; kt < 13; kt++) {
            for (int e = 0; e < 8; e++) {
                int k = kt * 32 + hi4 * 8 + e;
                float w = (k < HH) ? wrow[k] : 0.f;
                _Float16 wh = (_Float16)w;
                _Float16 wl = (_Float16)((w - (float)wh) * 2048.f);
                ahi[(kt * 64 + l) * 8 + e] = __builtin_bit_cast(unsigned short, wh);
                alo[(kt * 64 + l) * 8 + e] = __builtin_bit_cast(unsigned short, wl);
            }
        }
    }
    __syncthreads();

    float c_reg = 0.f;
    unsigned short* exh_d = exhi + (size_t)dir * 100 * 13 * 512;
    unsigned short* exl_d = exlo + (size_t)dir * 100 * 13 * 512;

    for (int s = 0; s < SS; s++) {
        const int time = dir ? (SS - 1 - s) : s;
        f32x4 gpre = *(const f32x4*)&G[(size_t)(b * SS + time) * G4 + hi4 * HH + j0];

        f32x4 acc;
        if (s > 0) {
            // wait for all 100 producers of this direction at step s-1:
            // all-lane loop, lane 0 loads, wave-wide ballot break (round-1 form)
            int* c4 = cnt + (dir * SS + (s - 1)) * 4;
            for (int guard = 0; guard < (1 << 20); guard++) {
                int sum = 0;
                if (l == 0) {
                    sum  = __hip_atomic_load(c4 + 0, __ATOMIC_RELAXED, __HIP_MEMORY_SCOPE_AGENT);
                    sum += __hip_atomic_load(c4 + 1, __ATOMIC_RELAXED, __HIP_MEMORY_SCOPE_AGENT);
                    sum += __hip_atomic_load(c4 + 2, __ATOMIC_RELAXED, __HIP_MEMORY_SCOPE_AGENT);
                    sum += __hip_atomic_load(c4 + 3, __ATOMIC_RELAXED, __HIP_MEMORY_SCOPE_AGENT);
                }
                if (__ballot(sum >= 100) & 1ull) break;
                __builtin_amdgcn_s_sleep(1);
            }
            asm volatile("" ::: "memory");   // no load hoisting above the poll

            const f16x8* __restrict__ pbh = (const f16x8*)(exh_d + (size_t)(s - 1) * 13 * 512);
            const f16x8* __restrict__ pbl = (const f16x8*)(exl_d + (size_t)(s - 1) * 13 * 512);
            f16x8 bh[13], bl[13];
#pragma unroll
            for (int kt = 0; kt < 13; kt++) {
                bh[kt] = pbh[kt * 64 + l];
                bl[kt] = pbl[kt * 64 + l];
            }
            f32x4 aHH = gpre;
            f32x4 aHL = {0.f, 0.f, 0.f, 0.f};
            f32x4 aLH = {0.f, 0.f, 0.f, 0.f};
#pragma unroll
            for (int kt = 0; kt < 13; kt++) {
                f16x8 wh = *(const f16x8*)&ahi[(kt * 64 + l) * 8];
                f16x8 wl = *(const f16x8*)&alo[(kt * 64 + l) * 8];
                aHH = __builtin_amdgcn_mfma_f32_16x16x32_f16(wh, bh[kt], aHH, 0, 0, 0);
                aHL = __builtin_amdgcn_mfma_f32_16x16x32_f16(wh, bl[kt], aHL, 0, 0, 0);
                aLH = __builtin_amdgcn_mfma_f32_16x16x32_f16(wl, bh[kt], aLH, 0, 0, 0);
            }
            acc = aHH + (aHL + aLH) * (1.f / 2048.f);
        } else {
            acc = gpre;   // h(-1) = 0
        }

#pragma unroll
        for (int q = 0; q < 4; q++) gl[(4 * hi4 + q) * 17 + b] = acc[q];
        __syncthreads();

        const int jj = hi4;
        float gi = gl[( 0 + jj) * 17 + b];
        float gf = gl[( 4 + jj) * 17 + b];
        float gg = gl[( 8 + jj) * 17 + b];
        float go = gl[(12 + jj) * 17 + b];
        __syncthreads();

        float si = 1.f / (1.f + expf(-gi));
        float sf = 1.f / (1.f + expf(-gf));
        float tg = tanhf(gg);
        float so = 1.f / (1.f + expf(-go));
        float c  = sf * c_reg + si * tg;
        c_reg = c;
        float h  = so * tanhf(c);

        hbuf[(size_t)(b * SS + time) * H2 + dir * HH + j0 + jj] = h;

        if (s < SS - 1) {
            _Float16 hh = (_Float16)h;
            _Float16 hl = (_Float16)((h - (float)hh) * 2048.f);
            unsigned uh = __builtin_bit_cast(unsigned short, hh);
            unsigned ul = __builtin_bit_cast(unsigned short, hl);
            unsigned ph = uh | (((unsigned)__shfl_down((int)uh, 16)) << 16);
            unsigned pl = ul | (((unsigned)__shfl_down((int)ul, 16)) << 16);
            if ((jj & 1) == 0) {
                int k0 = j0 + jj;
                int kt = k0 >> 5, ko = k0 & 31;
                int lg = ko >> 3, e = ko & 7;
                size_t u16idx = ((size_t)(s * 13 + kt) * 64 + (lg * 16 + b)) * 8 + e;
                __hip_atomic_store((unsigned*)(exh_d + u16idx), ph,
                                   __ATOMIC_RELAXED, __HIP_MEMORY_SCOPE_AGENT);
                __hip_atomic_store((unsigned*)(exl_d + u16idx), pl,
                                   __ATOMIC_RELAXED, __HIP_MEMORY_SCOPE_AGENT);
            }
            // h stores ACK'd at LLC before the counter inc becomes visible
            asm volatile("s_waitcnt vmcnt(0)" ::: "memory");
            if (l == 0)
                __hip_atomic_fetch_add(cnt + (dir * SS + s) * 4 + (wg & 3), 1,
                                       __ATOMIC_RELAXED, __HIP_MEMORY_SCOPE_AGENT);
        }
    }
}

// ---------------- attention scores ----------------
#define ITILE 11
__global__ __launch_bounds__(256) void attn_scores_kernel(
    const float* __restrict__ ua, const float* __restrict__ wa,
    const float* __restrict__ va, float* __restrict__ scores)
{
    int b  = blockIdx.x / 9;
    int i0 = (blockIdx.x % 9) * ITILE;
    int tid = threadIdx.x;
    __shared__ float ua_t[100][101];
    __shared__ float wa_t[ITILE][102];
    __shared__ float sacc[ITILE][101];
    __shared__ float va_t[100];

    for (int p = tid; p < ITILE * 101; p += 256) ((float*)sacc)[p] = 0.f;

    for (int ht = 0; ht < 8; ht++) {
        int h0 = ht * 100;
        __syncthreads();
        for (int p = tid; p < 100 * 100; p += 256) {
            int j = p / 100, hh = p % 100;
            ua_t[j][hh] = ua[(size_t)(b * SS + j) * H2 + h0 + hh];
        }
        for (int p = tid; p < ITILE * 100; p += 256) {
            int il = p / 100, hh = p % 100;
            wa_t[il][hh] = wa[(size_t)(b * SS + i0 + il + 1) * H2 + h0 + hh];
        }
        if (tid < 100) va_t[tid] = va[h0 + tid];
        __syncthreads();
        for (int p = tid; p < ITILE * 100; p += 256) {
            int il = p / 100, j = p % 100;
            float acc = 0.f;
#pragma unroll 4
            for (int hh = 0; hh < 100; hh++) {
                float x = ua_t[j][hh] + wa_t[il][hh];
                float z = __expf(2.f * x);
                float th = 1.f - 2.f * __builtin_amdgcn_rcpf(z + 1.f);
                acc = fmaf(th, va_t[hh], acc);
            }
            sacc[il][j] += acc;
        }
    }
    __syncthreads();
    for (int p = tid; p < ITILE * 100; p += 256) {
        int il = p / 100, j = p % 100;
        scores[(size_t)(b * 99 + i0 + il) * 100 + j] = sacc[il][j];
    }
}

// ---------------- softmax / table / preds / nll per (b,i) row ----------------
__global__ __launch_bounds__(128) void attn_softmax_kernel(
    const float* __restrict__ scores, const float* __restrict__ out2,
    const int* __restrict__ head, float* __restrict__ outb,
    float* __restrict__ nll)
{
    int bi = blockIdx.x;           // b*99 + i
    int b = bi / 99, i = bi % 99;
    int j = threadIdx.x;
    __shared__ float sv[128];
    __shared__ int   si[128];
    __shared__ float red[128];

    float h_t = out2[(size_t)(b * SS + i + 1) * H2];
    float sj = -1e30f;
    if (j < 100) {
        sj = scores[(size_t)bi * 100 + j];
        float h_j = out2[(size_t)(b * SS + j) * H2];
        if (h_j == h_t) sj = -10000.0f;
    }
    sv[j] = sj; si[j] = j;
    __syncthreads();
    for (int off = 64; off >= 1; off >>= 1) {
        if (j < off) {
            float o = sv[j + off]; int oi = si[j + off];
            if (o > sv[j] || (o == sv[j] && oi < si[j])) { sv[j] = o; si[j] = oi; }
        }
        __syncthreads();
    }
    float m = sv[0]; int amax = si[0];
    __syncthreads();
    float e = (j < 100) ? __expf(sj - m) : 0.f;
    red[j] = e;
    __syncthreads();
    for (int off = 64; off >= 1; off >>= 1) {
        if (j < off) red[j] += red[j + off];
        __syncthreads();
    }
    float sum = red[0];
    float inv = 1.f / sum;
    if (j < 100) outb[1 + 1584 + (size_t)bi * 100 + j] = e * inv;
    if (j == 0) {
        outb[1 + bi] = (float)amax;
        int gold = head[b * SS + i + 1];
        bool valid = (gold != -1);
        int gc = gold < 0 ? 0 : (gold > 99 ? 99 : gold);
        float sgc = scores[(size_t)bi * 100 + gc];
        float hgc = out2[(size_t)(b * SS + gc) * H2];
        if (hgc == h_t) sgc = -10000.0f;
        nll[bi] = valid ? -(sgc - m - logf(sum)) : 0.f;
    }
}

// ---------------- final loss reduction ----------------
__global__ __launch_bounds__(128) void loss_kernel(
    const float* __restrict__ nll, const int* __restrict__ head,
    float* __restrict__ outb)
{
    __shared__ float red[128];
    int tid = threadIdx.x;
    float contrib = 0.f;
    if (tid < 99) {
        int i = tid;
        float tot = 0.f; int cv = 0;
        for (int b = 0; b < BB; b++) {
            tot += nll[b * 99 + i];
            cv += (head[b * SS + i + 1] != -1) ? 1 : 0;
        }
        int denom = cv > 0 ? cv : 1;
        contrib = tot / (float)denom;
    }
    red[tid] = contrib;
    __syncthreads();
    for (int off = 64; off >= 1; off >>= 1) {
        if (tid < off) red[tid] += red[tid + off];
        __syncthreads();
    }
    if (tid == 0) outb[0] = red[0];
}

// ---------------- launch ----------------
extern "C" void kernel_launch(void* const* d_in, const int* in_sizes, int n_in,
                              void* d_out, int out_size, void* d_ws, size_t ws_size,
                              hipStream_t stream) {
    const int*   tok     = (const int*)d_in[0];
    const int*   pos     = (const int*)d_in[1];
    const int*   head    = (const int*)d_in[2];
    const float* word_W  = (const float*)d_in[3];
    const float* pos_W   = (const float*)d_in[4];
    const float* l0f_Wih = (const float*)d_in[5];
    const float* l0f_Whh = (const float*)d_in[6];
    const float* l0f_b   = (const float*)d_in[7];
    const float* l0b_Wih = (const float*)d_in[8];
    const float* l0b_Whh = (const float*)d_in[9];
    const float* l0b_b   = (const float*)d_in[10];
    const float* l1f_Wih = (const float*)d_in[11];
    const float* l1f_Whh = (const float*)d_in[12];
    const float* l1f_b   = (const float*)d_in[13];
    const float* l1b_Wih = (const float*)d_in[14];
    const float* l1b_Whh = (const float*)d_in[15];
    const float* l1b_b   = (const float*)d_in[16];
    const float* ua_W    = (const float*)d_in[17];
    const float* ua_b    = (const float*)d_in[18];
    const float* wa_W    = (const float*)d_in[19];
    const float* wa_b    = (const float*)d_in[20];
    const float* va_W    = (const float*)d_in[21];

    float* ws   = (float*)d_ws;
    float* x0   = ws + OFF_X0;
    float* gf   = ws + OFF_GF;   // also g1f, then ua
    float* gb   = ws + OFF_GB;   // also g1b, then wa
    float* h1   = ws + OFF_H1;
    float* out2 = ws + OFF_OUT2;
    float* sc   = ws + OFF_SC;
    float* nllb = ws + OFF_NLL;
    int*   cnt  = (int*)(ws + OFF_CNT);
    unsigned short* exhi = (unsigned short*)(ws + OFF_EXH);
    unsigned short* exlo = exhi + EX_U16_PER_PLANE;
    float* outf = (float*)d_out;

    hipMemsetAsync(cnt, 0, 1600 * sizeof(int), stream);
    // zero exchange planes (keeps padded-K tail zero so 0*tail can't make NaN)
    hipMemsetAsync(exhi, 0, 2 * EX_U16_PER_PLANE * sizeof(unsigned short), stream);

    embed_kernel<<<dim3((BB * SS * DIN0 + 255) / 256), 256, 0, stream>>>(
        tok, pos, word_W, pos_W, x0);

    // layer-0 input projections (K=150 -> fp32 VALU kernel)
    gemm_nt_bias<<<dim3(25, 25), 256, 0, stream>>>(x0, l0f_Wih, l0f_b, gf, 1600, DIN0, G4);
    gemm_nt_bias<<<dim3(25, 25), 256, 0, stream>>>(x0, l0b_Wih, l0b_b, gb, 1600, DIN0, G4);
    // layer-0 recurrence
    lstm_layer_kernel<<<dim3(200), 64, 0, stream>>>(
        gf, gb, l0f_Whh, l0b_Whh, h1, cnt, exhi, exlo);
    // layer-1 input projections (K=800 -> MFMA)
    gemm_nt_mfma<<<dim3(25, 25), 256, 0, stream>>>(h1, l1f_Wih, l1f_b, gf, 1600, H2, G4);
    gemm_nt_mfma<<<dim3(25, 25), 256, 0, stream>>>(h1, l1b_Wih, l1b_b, gb, 1600, H2, G4);
    // layer-1 recurrence
    lstm_layer_kernel<<<dim3(200), 64, 0, stream>>>(
        gf, gb, l1f_Whh, l1b_Whh, out2, cnt + 800, exhi, exlo);
    // attention projections (K=800 -> MFMA; R=800 -> 13 r-blocks, last half-idle)
    gemm_nt_mfma<<<dim3(13, 25), 256, 0, stream>>>(out2, ua_W, ua_b, gf, 1600, H2, H2);
    gemm_nt_mfma<<<dim3(13, 25), 256, 0, stream>>>(out2, wa_W, wa_b, gb, 1600, H2, H2);
    // scores, softmax/table/preds/nll, loss
    attn_scores_kernel<<<dim3(16 * 9), 256, 0, stream>>>(gf, gb, va_W, sc);
    attn_softmax_kernel<<<dim3(1584), 128, 0, stream>>>(sc, out2, head, outf, nllb);
    loss_kernel<<<dim3(1), 128, 0, stream>>>(nllb, head, outf);
}

// Round 6
// 1470.592 us; speedup vs baseline: 1.4557x; 1.0603x over previous
//
#include <hip/hip_runtime.h>

// ---------------- problem constants ----------------
#define BB 16
#define SS 100
#define HH 400      // hidden per direction
#define H2 800
#define G4 1600     // 4*H gate rows
#define DIN0 150    // WE+PE
#define KP0 160     // padded layer-0 K (150 -> 160, K%32==0)

// ---------------- workspace layout (float offsets) ----------------
#define OFF_X0   0ULL          // (unused now)
#define OFF_GF   240000ULL     // 2,560,000 (g0f / g1f / ua)
#define OFF_GB   2800000ULL    // 2,560,000 (g0b / g1b / wa)
#define OFF_H1   5360000ULL    // 1,280,000
#define OFF_OUT2 6640000ULL    // 1,280,000  (holds x0p/wfp/wbp until layer-1 LSTM writes it)
#define OFF_SC   7920000ULL    // 158,400
#define OFF_NLL  8078400ULL    // 1,600
#define OFF_CNT  8080000ULL    // 1,600 ints   } contiguous: one memset covers
#define OFF_EXH  8081600ULL    // u16 planes   } cnt + exhi + exlo
#define EX_U16_PER_PLANE 1331200ULL   // 2 dir * 100 steps * 13 kt * 64 * 8

// padded staging inside OUT2 (free until layer-1 recurrence writes out2)
#define PAD_X0   0ULL          // 1600*160 = 256,000 floats
#define PAD_WF   256000ULL     // 1600*160
#define PAD_WB   512000ULL     // 1600*160  (768,000 < 1,280,000 OK)

typedef _Float16 f16x8 __attribute__((ext_vector_type(8)));
typedef float    f32x4 __attribute__((ext_vector_type(4)));

// ---------------- embedding + layer-0 padding (one node) ----------------
// writes x0p[1600][160], wfp[1600][160], wbp[1600][160] (zero-padded K tail)
__global__ __launch_bounds__(256) void embed_pad_kernel(
    const int* __restrict__ tok, const int* __restrict__ pos,
    const float* __restrict__ wW, const float* __restrict__ pW,
    const float* __restrict__ Wf, const float* __restrict__ Wb,
    float* __restrict__ stage)   // OUT2 base
{
    int idx = blockIdx.x * 256 + threadIdx.x;
    if (idx >= 3 * 1600 * KP0) return;
    int which = idx / (1600 * KP0);
    int rem = idx % (1600 * KP0);
    int r = rem / KP0, k = rem % KP0;
    float v = 0.f;
    if (which == 0) {
        if (k < 100)       v = wW[tok[r] * 100 + k];
        else if (k < 150)  v = pW[pos[r] * 50 + (k - 100)];
        stage[PAD_X0 + (size_t)r * KP0 + k] = v;
    } else if (which == 1) {
        if (k < DIN0) v = Wf[r * DIN0 + k];
        stage[PAD_WF + (size_t)r * KP0 + k] = v;
    } else {
        if (k < DIN0) v = Wb[r * DIN0 + k];
        stage[PAD_WB + (size_t)r * KP0 + k] = v;
    }
}

// ---------------- f32 -> f16 hi/lo pair conversion (8 elems, scalar casts) ----------------
// w = hi + lo/2048 to ~2^-22 relative; lo pre-scaled x2048 stays in f16 normal range.
static __device__ __forceinline__ void cvt_pair8(float4 a, float4 b,
                                                 f16x8& hi, f16x8& lo)
{
    float v[8] = {a.x, a.y, a.z, a.w, b.x, b.y, b.z, b.w};
#pragma unroll
    for (int i = 0; i < 8; i++) {
        _Float16 h = (_Float16)v[i];
        hi[i] = h;
        lo[i] = (_Float16)((v[i] - (float)h) * 2048.f);
    }
}

// ---------------- dual MFMA NT GEMM (two W/bias/C sets, shared A) ----------------
// grid.x = 2*ceil(R/64); first half computes C0 = A@W0^T + b0, second half C1.
// Per block: 256 threads = 4 waves; wave w: output rows rs..rs+15, tokens n0..n0+63.
// f16 hi/lo 3-plane MFMA (fp32-equivalent). K % 32 == 0. No __syncthreads.
__global__ __launch_bounds__(256) void gemm_nt_mfma_dual(
    const float* __restrict__ A,
    const float* __restrict__ W0, const float* __restrict__ b0, float* __restrict__ C0,
    const float* __restrict__ W1, const float* __restrict__ b1, float* __restrict__ C1,
    int N, int K, int R)
{
    int half = gridDim.x >> 1;
    int sel = blockIdx.x >= half;
    int bx = blockIdx.x - (sel ? half : 0);
    const float* W = sel ? W1 : W0;
    const float* bias = sel ? b1 : b0;
    float* C = sel ? C1 : C0;

    int tid = threadIdx.x;
    int wv = tid >> 6, l = tid & 63;
    int lm = l & 15, lk = l >> 4;
    int rs = bx * 64 + wv * 16;
    if (rs >= R) return;
    int n0 = blockIdx.y * 64;

    const float* wrow = W + (size_t)(rs + lm) * K + lk * 8;
    const float* arow = A + (size_t)(n0 + lm) * K + lk * 8;

    f32x4 accH[4], accX[4];
#pragma unroll
    for (int ct = 0; ct < 4; ct++) {
        accH[ct] = {0.f, 0.f, 0.f, 0.f};
        accX[ct] = {0.f, 0.f, 0.f, 0.f};
    }

    int ksteps = K >> 5;
    for (int kt = 0; kt < ksteps; kt++) {
        int kb = kt << 5;
        float4 wlo4 = *(const float4*)(wrow + kb);
        float4 whi4 = *(const float4*)(wrow + kb + 4);
        f16x8 wh, wl;
        cvt_pair8(wlo4, whi4, wh, wl);
#pragma unroll
        for (int ct = 0; ct < 4; ct++) {
            const float* ap = arow + (size_t)(ct * 16) * K + kb;
            float4 aa = *(const float4*)ap;
            float4 ab = *(const float4*)(ap + 4);
            f16x8 ah, al;
            cvt_pair8(aa, ab, ah, al);
            accH[ct] = __builtin_amdgcn_mfma_f32_16x16x32_f16(wh, ah, accH[ct], 0, 0, 0);
            accX[ct] = __builtin_amdgcn_mfma_f32_16x16x32_f16(wh, al, accX[ct], 0, 0, 0);
            accX[ct] = __builtin_amdgcn_mfma_f32_16x16x32_f16(wl, ah, accX[ct], 0, 0, 0);
        }
    }

    float4 bv = *(const float4*)&bias[rs + lk * 4];
#pragma unroll
    for (int ct = 0; ct < 4; ct++) {
        f32x4 v = accH[ct] + accX[ct] * (1.f / 2048.f);
        float4 o;
        o.x = v[0] + bv.x; o.y = v[1] + bv.y; o.z = v[2] + bv.z; o.w = v[3] + bv.w;
        *(float4*)&C[(size_t)(n0 + ct * 16 + lm) * R + rs + lk * 4] = o;
    }
}

// ---------------- LSTM recurrence: MFMA f16 hi/lo split, counter step barrier ----------------
// EXACT round-5 verified version (455 us/dispatch). DO NOT TOUCH (control).
// Producer signal is RELAXED fetch_add: the preceding s_waitcnt vmcnt(0) already
// orders the LLC-scope h stores; a RELEASE RMW at agent scope adds an L2 writeback
// (buffer_wbl2) per step per WG -> +300 us/dispatch (measured round 4).
__global__ __launch_bounds__(64, 1) void lstm_layer_kernel(
    const float* __restrict__ Gf, const float* __restrict__ Gb,
    const float* __restrict__ Wf, const float* __restrict__ Wb,
    float* __restrict__ hbuf,          // [B][S][800] fp32 for downstream kernels
    int* __restrict__ cnt,             // [2][100][4] step counters
    unsigned short* __restrict__ exhi, // f16 hi plane, frag layout [dir][s][kt][64][8]
    unsigned short* __restrict__ exlo) // f16 lo plane (x2048)
{
    const int dir = blockIdx.x / 100;
    const int wg  = blockIdx.x % 100;
    const int j0  = wg * 4;
    const float* __restrict__ G = dir ? Gb : Gf;
    const float* __restrict__ W = dir ? Wb : Wf;

    const int l   = threadIdx.x;   // 0..63
    const int b   = l & 15;
    const int hi4 = l >> 4;

    __shared__ __attribute__((aligned(16))) unsigned short ahi[13 * 64 * 8];
    __shared__ __attribute__((aligned(16))) unsigned short alo[13 * 64 * 8];
    __shared__ float gl[16 * 17];

    // ---- one-time: weights -> f16 hi/lo A-fragments in LDS ----
    {
        const int m = b;
        const int g = m >> 2, jj = m & 3;
        const float* wrow = W + (size_t)(g * HH + j0 + jj) * HH;
        for (int kt = 0; kt < 13; kt++) {
            for (int e = 0; e < 8; e++) {
                int k = kt * 32 + hi4 * 8 + e;
                float w = (k < HH) ? wrow[k] : 0.f;
                _Float16 wh = (_Float16)w;
                _Float16 wl = (_Float16)((w - (float)wh) * 2048.f);
                ahi[(kt * 64 + l) * 8 + e] = __builtin_bit_cast(unsigned short, wh);
                alo[(kt * 64 + l) * 8 + e] = __builtin_bit_cast(unsigned short, wl);
            }
        }
    }
    __syncthreads();

    float c_reg = 0.f;
    unsigned short* exh_d = exhi + (size_t)dir * 100 * 13 * 512;
    unsigned short* exl_d = exlo + (size_t)dir * 100 * 13 * 512;

    for (int s = 0; s < SS; s++) {
        const int time = dir ? (SS - 1 - s) : s;
        f32x4 gpre = *(const f32x4*)&G[(size_t)(b * SS + time) * G4 + hi4 * HH + j0];

        f32x4 acc;
        if (s > 0) {
            // wait for all 100 producers of this direction at step s-1:
            // all-lane loop, lane 0 loads, wave-wide ballot break
            int* c4 = cnt + (dir * SS + (s - 1)) * 4;
            for (int guard = 0; guard < (1 << 20); guard++) {
                int sum = 0;
                if (l == 0) {
                    sum  = __hip_atomic_load(c4 + 0, __ATOMIC_RELAXED, __HIP_MEMORY_SCOPE_AGENT);
                    sum += __hip_atomic_load(c4 + 1, __ATOMIC_RELAXED, __HIP_MEMORY_SCOPE_AGENT);
                    sum += __hip_atomic_load(c4 + 2, __ATOMIC_RELAXED, __HIP_MEMORY_SCOPE_AGENT);
                    sum += __hip_atomic_load(c4 + 3, __ATOMIC_RELAXED, __HIP_MEMORY_SCOPE_AGENT);
                }
                if (__ballot(sum >= 100) & 1ull) break;
                __builtin_amdgcn_s_sleep(1);
            }
            asm volatile("" ::: "memory");   // no load hoisting above the poll

            const f16x8* __restrict__ pbh = (const f16x8*)(exh_d + (size_t)(s - 1) * 13 * 512);
            const f16x8* __restrict__ pbl = (const f16x8*)(exl_d + (size_t)(s - 1) * 13 * 512);
            f16x8 bh[13], bl[13];
#pragma unroll
            for (int kt = 0; kt < 13; kt++) {
                bh[kt] = pbh[kt * 64 + l];
                bl[kt] = pbl[kt * 64 + l];
            }
            f32x4 aHH = gpre;
            f32x4 aHL = {0.f, 0.f, 0.f, 0.f};
            f32x4 aLH = {0.f, 0.f, 0.f, 0.f};
#pragma unroll
            for (int kt = 0; kt < 13; kt++) {
                f16x8 wh = *(const f16x8*)&ahi[(kt * 64 + l) * 8];
                f16x8 wl = *(const f16x8*)&alo[(kt * 64 + l) * 8];
                aHH = __builtin_amdgcn_mfma_f32_16x16x32_f16(wh, bh[kt], aHH, 0, 0, 0);
                aHL = __builtin_amdgcn_mfma_f32_16x16x32_f16(wh, bl[kt], aHL, 0, 0, 0);
                aLH = __builtin_amdgcn_mfma_f32_16x16x32_f16(wl, bh[kt], aLH, 0, 0, 0);
            }
            acc = aHH + (aHL + aLH) * (1.f / 2048.f);
        } else {
            acc = gpre;   // h(-1) = 0
        }

#pragma unroll
        for (int q = 0; q < 4; q++) gl[(4 * hi4 + q) * 17 + b] = acc[q];
        __syncthreads();

        const int jj = hi4;
        float gi = gl[( 0 + jj) * 17 + b];
        float gf = gl[( 4 + jj) * 17 + b];
        float gg = gl[( 8 + jj) * 17 + b];
        float go = gl[(12 + jj) * 17 + b];
        __syncthreads();

        float si = 1.f / (1.f + expf(-gi));
        float sf = 1.f / (1.f + expf(-gf));
        float tg = tanhf(gg);
        float so = 1.f / (1.f + expf(-go));
        float c  = sf * c_reg + si * tg;
        c_reg = c;
        float h  = so * tanhf(c);

        hbuf[(size_t)(b * SS + time) * H2 + dir * HH + j0 + jj] = h;

        if (s < SS - 1) {
            _Float16 hh = (_Float16)h;
            _Float16 hl = (_Float16)((h - (float)hh) * 2048.f);
            unsigned uh = __builtin_bit_cast(unsigned short, hh);
            unsigned ul = __builtin_bit_cast(unsigned short, hl);
            unsigned ph = uh | (((unsigned)__shfl_down((int)uh, 16)) << 16);
            unsigned pl = ul | (((unsigned)__shfl_down((int)ul, 16)) << 16);
            if ((jj & 1) == 0) {
                int k0 = j0 + jj;
                int kt = k0 >> 5, ko = k0 & 31;
                int lg = ko >> 3, e = ko & 7;
                size_t u16idx = ((size_t)(s * 13 + kt) * 64 + (lg * 16 + b)) * 8 + e;
                __hip_atomic_store((unsigned*)(exh_d + u16idx), ph,
                                   __ATOMIC_RELAXED, __HIP_MEMORY_SCOPE_AGENT);
                __hip_atomic_store((unsigned*)(exl_d + u16idx), pl,
                                   __ATOMIC_RELAXED, __HIP_MEMORY_SCOPE_AGENT);
            }
            // h stores ACK'd at LLC before the counter inc becomes visible
            asm volatile("s_waitcnt vmcnt(0)" ::: "memory");
            if (l == 0)
                __hip_atomic_fetch_add(cnt + (dir * SS + s) * 4 + (wg & 3), 1,
                                       __ATOMIC_RELAXED, __HIP_MEMORY_SCOPE_AGENT);
        }
    }
}

// ---------------- attention scores ----------------
#define ITILE 11
__global__ __launch_bounds__(256) void attn_scores_kernel(
    const float* __restrict__ ua, const float* __restrict__ wa,
    const float* __restrict__ va, float* __restrict__ scores)
{
    int b  = blockIdx.x / 9;
    int i0 = (blockIdx.x % 9) * ITILE;
    int tid = threadIdx.x;
    __shared__ float ua_t[100][101];
    __shared__ float wa_t[ITILE][102];
    __shared__ float sacc[ITILE][101];
    __shared__ float va_t[100];

    for (int p = tid; p < ITILE * 101; p += 256) ((float*)sacc)[p] = 0.f;

    for (int ht = 0; ht < 8; ht++) {
        int h0 = ht * 100;
        __syncthreads();
        for (int p = tid; p < 100 * 100; p += 256) {
            int j = p / 100, hh = p % 100;
            ua_t[j][hh] = ua[(size_t)(b * SS + j) * H2 + h0 + hh];
        }
        for (int p = tid; p < ITILE * 100; p += 256) {
            int il = p / 100, hh = p % 100;
            wa_t[il][hh] = wa[(size_t)(b * SS + i0 + il + 1) * H2 + h0 + hh];
        }
        if (tid < 100) va_t[tid] = va[h0 + tid];
        __syncthreads();
        for (int p = tid; p < ITILE * 100; p += 256) {
            int il = p / 100, j = p % 100;
            float acc = 0.f;
#pragma unroll 4
            for (int hh = 0; hh < 100; hh++) {
                float x = ua_t[j][hh] + wa_t[il][hh];
                float z = __expf(2.f * x);
                float th = 1.f - 2.f * __builtin_amdgcn_rcpf(z + 1.f);
                acc = fmaf(th, va_t[hh], acc);
            }
            sacc[il][j] += acc;
        }
    }
    __syncthreads();
    for (int p = tid; p < ITILE * 100; p += 256) {
        int il = p / 100, j = p % 100;
        scores[(size_t)(b * 99 + i0 + il) * 100 + j] = sacc[il][j];
    }
}

// ---------------- softmax / table / preds / nll per (b,i) row ----------------
__global__ __launch_bounds__(128) void attn_softmax_kernel(
    const float* __restrict__ scores, const float* __restrict__ out2,
    const int* __restrict__ head, float* __restrict__ outb,
    float* __restrict__ nll)
{
    int bi = blockIdx.x;           // b*99 + i
    int b = bi / 99, i = bi % 99;
    int j = threadIdx.x;
    __shared__ float sv[128];
    __shared__ int   si[128];
    __shared__ float red[128];

    float h_t = out2[(size_t)(b * SS + i + 1) * H2];
    float sj = -1e30f;
    if (j < 100) {
        sj = scores[(size_t)bi * 100 + j];
        float h_j = out2[(size_t)(b * SS + j) * H2];
        if (h_j == h_t) sj = -10000.0f;
    }
    sv[j] = sj; si[j] = j;
    __syncthreads();
    for (int off = 64; off >= 1; off >>= 1) {
        if (j < off) {
            float o = sv[j + off]; int oi = si[j + off];
            if (o > sv[j] || (o == sv[j] && oi < si[j])) { sv[j] = o; si[j] = oi; }
        }
        __syncthreads();
    }
    float m = sv[0]; int amax = si[0];
    __syncthreads();
    float e = (j < 100) ? __expf(sj - m) : 0.f;
    red[j] = e;
    __syncthreads();
    for (int off = 64; off >= 1; off >>= 1) {
        if (j < off) red[j] += red[j + off];
        __syncthreads();
    }
    float sum = red[0];
    float inv = 1.f / sum;
    if (j < 100) outb[1 + 1584 + (size_t)bi * 100 + j] = e * inv;
    if (j == 0) {
        outb[1 + bi] = (float)amax;
        int gold = head[b * SS + i + 1];
        bool valid = (gold != -1);
        int gc = gold < 0 ? 0 : (gold > 99 ? 99 : gold);
        float sgc = scores[(size_t)bi * 100 + gc];
        float hgc = out2[(size_t)(b * SS + gc) * H2];
        if (hgc == h_t) sgc = -10000.0f;
        nll[bi] = valid ? -(sgc - m - logf(sum)) : 0.f;
    }
}

// ---------------- final loss reduction ----------------
__global__ __launch_bounds__(128) void loss_kernel(
    const float* __restrict__ nll, const int* __restrict__ head,
    float* __restrict__ outb)
{
    __shared__ float red[128];
    int tid = threadIdx.x;
    float contrib = 0.f;
    if (tid < 99) {
        int i = tid;
        float tot = 0.f; int cv = 0;
        for (int b = 0; b < BB; b++) {
            tot += nll[b * 99 + i];
            cv += (head[b * SS + i + 1] != -1) ? 1 : 0;
        }
        int denom = cv > 0 ? cv : 1;
        contrib = tot / (float)denom;
    }
    red[tid] = contrib;
    __syncthreads();
    for (int off = 64; off >= 1; off >>= 1) {
        if (tid < off) red[tid] += red[tid + off];
        __syncthreads();
    }
    if (tid == 0) outb[0] = red[0];
}

// ---------------- launch ----------------
extern "C" void kernel_launch(void* const* d_in, const int* in_sizes, int n_in,
                              void* d_out, int out_size, void* d_ws, size_t ws_size,
                              hipStream_t stream) {
    const int*   tok     = (const int*)d_in[0];
    const int*   pos     = (const int*)d_in[1];
    const int*   head    = (const int*)d_in[2];
    const float* word_W  = (const float*)d_in[3];
    const float* pos_W   = (const float*)d_in[4];
    const float* l0f_Wih = (const float*)d_in[5];
    const float* l0f_Whh = (const float*)d_in[6];
    const float* l0f_b   = (const float*)d_in[7];
    const float* l0b_Wih = (const float*)d_in[8];
    const float* l0b_Whh = (const float*)d_in[9];
    const float* l0b_b   = (const float*)d_in[10];
    const float* l1f_Wih = (const float*)d_in[11];
    const float* l1f_Whh = (const float*)d_in[12];
    const float* l1f_b   = (const float*)d_in[13];
    const float* l1b_Wih = (const float*)d_in[14];
    const float* l1b_Whh = (const float*)d_in[15];
    const float* l1b_b   = (const float*)d_in[16];
    const float* ua_W    = (const float*)d_in[17];
    const float* ua_b    = (const float*)d_in[18];
    const float* wa_W    = (const float*)d_in[19];
    const float* wa_b    = (const float*)d_in[20];
    const float* va_W    = (const float*)d_in[21];

    float* ws   = (float*)d_ws;
    float* gf   = ws + OFF_GF;   // g0f / g1f / ua
    float* gb   = ws + OFF_GB;   // g0b / g1b / wa
    float* h1   = ws + OFF_H1;
    float* out2 = ws + OFF_OUT2; // also x0p/wfp/wbp staging before layer-1 LSTM
    float* sc   = ws + OFF_SC;
    float* nllb = ws + OFF_NLL;
    int*   cnt  = (int*)(ws + OFF_CNT);
    unsigned short* exhi = (unsigned short*)(ws + OFF_EXH);
    unsigned short* exlo = exhi + EX_U16_PER_PLANE;
    float* outf = (float*)d_out;

    // cnt + exhi + exlo are contiguous: one memset (counters zeroed for graph
    // replay; exchange planes zeroed so the padded-K tail can't make NaN)
    hipMemsetAsync(cnt, 0, 1600 * sizeof(int) + 2 * EX_U16_PER_PLANE * sizeof(unsigned short), stream);

    // embedding (K=160-padded) + zero-padded layer-0 Wih copies, staged in OUT2
    embed_pad_kernel<<<dim3((3 * 1600 * KP0 + 255) / 256), 256, 0, stream>>>(
        tok, pos, word_W, pos_W, l0f_Wih, l0b_Wih, out2);

    float* x0p = out2 + PAD_X0;
    float* wfp = out2 + PAD_WF;
    float* wbp = out2 + PAD_WB;

    // layer-0 input projections (MFMA, K=160, fused f+b)
    gemm_nt_mfma_dual<<<dim3(50, 25), 256, 0, stream>>>(
        x0p, wfp, l0f_b, gf, wbp, l0b_b, gb, 1600, KP0, G4);
    // layer-0 recurrence
    lstm_layer_kernel<<<dim3(200), 64, 0, stream>>>(
        gf, gb, l0f_Whh, l0b_Whh, h1, cnt, exhi, exlo);
    // layer-1 input projections (MFMA, K=800, fused f+b)
    gemm_nt_mfma_dual<<<dim3(50, 25), 256, 0, stream>>>(
        h1, l1f_Wih, l1f_b, gf, l1b_Wih, l1b_b, gb, 1600, H2, G4);
    // layer-1 recurrence (overwrites the x0p/wfp/wbp staging -- by now unused)
    lstm_layer_kernel<<<dim3(200), 64, 0, stream>>>(
        gf, gb, l1f_Whh, l1b_Whh, out2, cnt + 800, exhi, exlo);
    // attention projections (MFMA, K=800, R=800, fused ua+wa)
    gemm_nt_mfma_dual<<<dim3(26, 25), 256, 0, stream>>>(
        out2, ua_W, ua_b, gf, wa_W, wa_b, gb, 1600, H2, H2);
    // scores, softmax/table/preds/nll, loss
    attn_scores_kernel<<<dim3(16 * 9), 256, 0, stream>>>(gf, gb, va_W, sc);
    attn_softmax_kernel<<<dim3(1584), 128, 0, stream>>>(sc, out2, head, outf, nllb);
    loss_kernel<<<dim3(1), 128, 0, stream>>>(nllb, head, outf);
}

// Round 9
// 1440.469 us; speedup vs baseline: 1.4862x; 1.0209x over previous
//
#include <hip/hip_runtime.h>

// ---------------- problem constants ----------------
#define BB 16
#define SS 100
#define HH 400      // hidden per direction
#define H2 800
#define G4 1600     // 4*H gate rows
#define DIN0 150    // WE+PE
#define KP0 160     // padded layer-0 K (150 -> 160, K%32==0)

// ---------------- workspace layout (float offsets) ----------------
#define OFF_GF   240000ULL     // 2,560,000 (g0f / g1f / ua)
#define OFF_GB   2800000ULL    // 2,560,000 (g0b / g1b / wa)
#define OFF_H1   5360000ULL    // 1,280,000
#define OFF_OUT2 6640000ULL    // 1,280,000  (holds x0p/wfp/wbp until layer-1 LSTM writes it)
#define OFF_SC   7920000ULL    // 158,400
#define OFF_NLL  8078400ULL    // 1,600
#define OFF_EXH  8081600ULL    // u16 exchange planes (exhi then exlo, contiguous)
#define EX_U16_PER_PLANE 1331200ULL   // 2 dir * 100 steps * 13 kt * 64 * 8

// padded staging inside OUT2 (free until layer-1 recurrence writes out2)
#define PAD_X0   0ULL
#define PAD_WF   256000ULL
#define PAD_WB   512000ULL

typedef _Float16 f16x8 __attribute__((ext_vector_type(8)));
typedef float    f32x4 __attribute__((ext_vector_type(4)));
typedef unsigned long long u64x2 __attribute__((ext_vector_type(2)));

// poison check: u32 half == 0xFFFFFFFF (two f16 NaNs -- unreachable by real data:
// hi = f16(h) finite, lo = f16((h-hi)*2048) finite)
static __device__ __forceinline__ unsigned chkp(unsigned long long q) {
    return ((unsigned)q == 0xFFFFFFFFu) | ((unsigned)(q >> 32) == 0xFFFFFFFFu);
}
// zero any poison halves (sanity rail: turns a liveness bug into bounded error)
static __device__ __forceinline__ unsigned long long sanq(unsigned long long q) {
    if ((unsigned)q == 0xFFFFFFFFu)         q &= 0xFFFFFFFF00000000ull;
    if ((unsigned)(q >> 32) == 0xFFFFFFFFu) q &= 0x00000000FFFFFFFFull;
    return q;
}

// ---------------- embedding + layer-0 padding (one node) ----------------
__global__ __launch_bounds__(256) void embed_pad_kernel(
    const int* __restrict__ tok, const int* __restrict__ pos,
    const float* __restrict__ wW, const float* __restrict__ pW,
    const float* __restrict__ Wf, const float* __restrict__ Wb,
    float* __restrict__ stage)   // OUT2 base
{
    int idx = blockIdx.x * 256 + threadIdx.x;
    if (idx >= 3 * 1600 * KP0) return;
    int which = idx / (1600 * KP0);
    int rem = idx % (1600 * KP0);
    int r = rem / KP0, k = rem % KP0;
    float v = 0.f;
    if (which == 0) {
        if (k < 100)       v = wW[tok[r] * 100 + k];
        else if (k < 150)  v = pW[pos[r] * 50 + (k - 100)];
        stage[PAD_X0 + (size_t)r * KP0 + k] = v;
    } else if (which == 1) {
        if (k < DIN0) v = Wf[r * DIN0 + k];
        stage[PAD_WF + (size_t)r * KP0 + k] = v;
    } else {
        if (k < DIN0) v = Wb[r * DIN0 + k];
        stage[PAD_WB + (size_t)r * KP0 + k] = v;
    }
}

// ---------------- f32 -> f16 hi/lo pair conversion ----------------
static __device__ __forceinline__ void cvt_pair8(float4 a, float4 b,
                                                 f16x8& hi, f16x8& lo)
{
    float v[8] = {a.x, a.y, a.z, a.w, b.x, b.y, b.z, b.w};
#pragma unroll
    for (int i = 0; i < 8; i++) {
        _Float16 h = (_Float16)v[i];
        hi[i] = h;
        lo[i] = (_Float16)((v[i] - (float)h) * 2048.f);
    }
}

// ---------------- dual MFMA NT GEMM (+ optional exchange re-poison) ----------------
__global__ __launch_bounds__(256) void gemm_nt_mfma_dual(
    const float* __restrict__ A,
    const float* __restrict__ W0, const float* __restrict__ b0, float* __restrict__ C0,
    const float* __restrict__ W1, const float* __restrict__ b1, float* __restrict__ C1,
    int N, int K, int R,
    unsigned int* __restrict__ poison, int poison_words)
{
    if (poison) {
        int nthreads = gridDim.x * gridDim.y * 256;
        int gtid = (blockIdx.y * gridDim.x + blockIdx.x) * 256 + threadIdx.x;
        for (int i = gtid; i < poison_words; i += nthreads) poison[i] = 0xFFFFFFFFu;
    }

    int half = gridDim.x >> 1;
    int sel = blockIdx.x >= half;
    int bx = blockIdx.x - (sel ? half : 0);
    const float* W = sel ? W1 : W0;
    const float* bias = sel ? b1 : b0;
    float* C = sel ? C1 : C0;

    int tid = threadIdx.x;
    int wv = tid >> 6, l = tid & 63;
    int lm = l & 15, lk = l >> 4;
    int rs = bx * 64 + wv * 16;
    if (rs >= R) return;
    int n0 = blockIdx.y * 64;

    const float* wrow = W + (size_t)(rs + lm) * K + lk * 8;
    const float* arow = A + (size_t)(n0 + lm) * K + lk * 8;

    f32x4 accH[4], accX[4];
#pragma unroll
    for (int ct = 0; ct < 4; ct++) {
        accH[ct] = {0.f, 0.f, 0.f, 0.f};
        accX[ct] = {0.f, 0.f, 0.f, 0.f};
    }

    int ksteps = K >> 5;
    for (int kt = 0; kt < ksteps; kt++) {
        int kb = kt << 5;
        float4 wlo4 = *(const float4*)(wrow + kb);
        float4 whi4 = *(const float4*)(wrow + kb + 4);
        f16x8 wh, wl;
        cvt_pair8(wlo4, whi4, wh, wl);
#pragma unroll
        for (int ct = 0; ct < 4; ct++) {
            const float* ap = arow + (size_t)(ct * 16) * K + kb;
            float4 aa = *(const float4*)ap;
            float4 ab = *(const float4*)(ap + 4);
            f16x8 ah, al;
            cvt_pair8(aa, ab, ah, al);
            accH[ct] = __builtin_amdgcn_mfma_f32_16x16x32_f16(wh, ah, accH[ct], 0, 0, 0);
            accX[ct] = __builtin_amdgcn_mfma_f32_16x16x32_f16(wh, al, accX[ct], 0, 0, 0);
            accX[ct] = __builtin_amdgcn_mfma_f32_16x16x32_f16(wl, ah, accX[ct], 0, 0, 0);
        }
    }

    float4 bv = *(const float4*)&bias[rs + lk * 4];
#pragma unroll
    for (int ct = 0; ct < 4; ct++) {
        f32x4 v = accH[ct] + accX[ct] * (1.f / 2048.f);
        float4 o;
        o.x = v[0] + bv.x; o.y = v[1] + bv.y; o.z = v[2] + bv.z; o.w = v[3] + bv.w;
        *(float4*)&C[(size_t)(n0 + ct * 16 + lm) * R + rs + lk * 4] = o;
    }
}

// ---------------- LSTM recurrence: MFMA f16 hi/lo, in-band poison sync ----------------
// Validity is in-band: exchange planes pre-poisoned to 0xFFFFFFFF; producers
// fire-and-forget relaxed agent-scope u32 stores; consumers poll the data itself
// with agent-scope u64 loads until no word is poison, then feed the same registers
// to MFMA. One LLC hop per step instead of three.
// SAFETY RAILS (round-8 container death): guard capped at 2^13 (bounded spin),
// s_sleep(2) backoff on failed detect (poll traffic can't starve producers),
// sanitize-on-exhaustion (poison -> 0, never NaN, absmax-visible).
// PAD RULE: kt=12 covers k=384..415; k>=400 (lanes hi4>=2) is never written --
// those lanes skip the check and use ZERO operands (LDS weights there are 0 too).
__global__ __launch_bounds__(64, 1) void lstm_layer_kernel(
    const float* __restrict__ Gf, const float* __restrict__ Gb,
    const float* __restrict__ Wf, const float* __restrict__ Wb,
    float* __restrict__ hbuf,          // [B][S][800] fp32 for downstream kernels
    unsigned short* __restrict__ exhi, // f16 hi plane, frag layout [dir][s][kt][64][8]
    unsigned short* __restrict__ exlo) // f16 lo plane (x2048)
{
    const int dir = blockIdx.x / 100;
    const int wg  = blockIdx.x % 100;
    const int j0  = wg * 4;
    const float* __restrict__ G = dir ? Gb : Gf;
    const float* __restrict__ W = dir ? Wb : Wf;

    const int l   = threadIdx.x;   // 0..63
    const int b   = l & 15;
    const int hi4 = l >> 4;

    __shared__ __attribute__((aligned(16))) unsigned short ahi[13 * 64 * 8];
    __shared__ __attribute__((aligned(16))) unsigned short alo[13 * 64 * 8];
    __shared__ float gl[16 * 17];

    // ---- one-time: weights -> f16 hi/lo A-fragments in LDS ----
    {
        const int m = b;
        const int g = m >> 2, jj = m & 3;
        const float* wrow = W + (size_t)(g * HH + j0 + jj) * HH;
        for (int kt = 0; kt < 13; kt++) {
            for (int e = 0; e < 8; e++) {
                int k = kt * 32 + hi4 * 8 + e;
                float w = (k < HH) ? wrow[k] : 0.f;
                _Float16 wh = (_Float16)w;
                _Float16 wl = (_Float16)((w - (float)wh) * 2048.f);
                ahi[(kt * 64 + l) * 8 + e] = __builtin_bit_cast(unsigned short, wh);
                alo[(kt * 64 + l) * 8 + e] = __builtin_bit_cast(unsigned short, wl);
            }
        }
    }
    __syncthreads();

    float c_reg = 0.f;
    unsigned short* exh_d = exhi + (size_t)dir * 100 * 13 * 512;
    unsigned short* exl_d = exlo + (size_t)dir * 100 * 13 * 512;
    const int pad_lane = (hi4 >= 2);   // kt=12 k-range 400..415 for this lane

    for (int s = 0; s < SS; s++) {
        const int time = dir ? (SS - 1 - s) : s;
        f32x4 gpre = *(const f32x4*)&G[(size_t)(b * SS + time) * G4 + hi4 * HH + j0];

        f32x4 acc;
        if (s > 0) {
            const unsigned long long* pbh =
                (const unsigned long long*)(exh_d + (size_t)(s - 1) * 13 * 512);
            const unsigned long long* pbl =
                (const unsigned long long*)(exl_d + (size_t)(s - 1) * 13 * 512);
            u64x2 vh2[13], vl2[13];
            vh2[12] = {0ull, 0ull};    // pad lanes keep zeros (0 * w = 0)
            vl2[12] = {0ull, 0ull};
            unsigned bad = 1;
            for (int guard = 0; guard < (1 << 13); guard++) {
                bad = 0;
#pragma unroll
                for (int kt = 0; kt < 12; kt++) {
                    size_t q = (size_t)(kt * 64 + l) * 2;
                    vh2[kt][0] = __hip_atomic_load(pbh + q,     __ATOMIC_RELAXED, __HIP_MEMORY_SCOPE_AGENT);
                    vh2[kt][1] = __hip_atomic_load(pbh + q + 1, __ATOMIC_RELAXED, __HIP_MEMORY_SCOPE_AGENT);
                    vl2[kt][0] = __hip_atomic_load(pbl + q,     __ATOMIC_RELAXED, __HIP_MEMORY_SCOPE_AGENT);
                    vl2[kt][1] = __hip_atomic_load(pbl + q + 1, __ATOMIC_RELAXED, __HIP_MEMORY_SCOPE_AGENT);
                }
                if (!pad_lane) {
                    size_t q = (size_t)(12 * 64 + l) * 2;
                    vh2[12][0] = __hip_atomic_load(pbh + q,     __ATOMIC_RELAXED, __HIP_MEMORY_SCOPE_AGENT);
                    vh2[12][1] = __hip_atomic_load(pbh + q + 1, __ATOMIC_RELAXED, __HIP_MEMORY_SCOPE_AGENT);
                    vl2[12][0] = __hip_atomic_load(pbl + q,     __ATOMIC_RELAXED, __HIP_MEMORY_SCOPE_AGENT);
                    vl2[12][1] = __hip_atomic_load(pbl + q + 1, __ATOMIC_RELAXED, __HIP_MEMORY_SCOPE_AGENT);
                    bad |= chkp(vh2[12][0]) | chkp(vh2[12][1])
                         | chkp(vl2[12][0]) | chkp(vl2[12][1]);
                }
#pragma unroll
                for (int kt = 0; kt < 12; kt++) {
                    bad |= chkp(vh2[kt][0]) | chkp(vh2[kt][1])
                         | chkp(vl2[kt][0]) | chkp(vl2[kt][1]);
                }
                if (__ballot(bad != 0) == 0ull) break;
                __builtin_amdgcn_s_sleep(2);   // backoff: don't flood the LLC
            }
            if (bad) {                         // rail: never feed NaN to MFMA
#pragma unroll
                for (int kt = 0; kt < 13; kt++) {
                    vh2[kt][0] = sanq(vh2[kt][0]); vh2[kt][1] = sanq(vh2[kt][1]);
                    vl2[kt][0] = sanq(vl2[kt][0]); vl2[kt][1] = sanq(vl2[kt][1]);
                }
            }
            asm volatile("" ::: "memory");

            f32x4 aHH = gpre;
            f32x4 aHL = {0.f, 0.f, 0.f, 0.f};
            f32x4 aLH = {0.f, 0.f, 0.f, 0.f};
#pragma unroll
            for (int kt = 0; kt < 13; kt++) {
                f16x8 bhv = __builtin_bit_cast(f16x8, vh2[kt]);
                f16x8 blv = __builtin_bit_cast(f16x8, vl2[kt]);
                f16x8 wh = *(const f16x8*)&ahi[(kt * 64 + l) * 8];
                f16x8 wl = *(const f16x8*)&alo[(kt * 64 + l) * 8];
                aHH = __builtin_amdgcn_mfma_f32_16x16x32_f16(wh, bhv, aHH, 0, 0, 0);
                aHL = __builtin_amdgcn_mfma_f32_16x16x32_f16(wh, blv, aHL, 0, 0, 0);
                aLH = __builtin_amdgcn_mfma_f32_16x16x32_f16(wl, bhv, aLH, 0, 0, 0);
            }
            acc = aHH + (aHL + aLH) * (1.f / 2048.f);
        } else {
            acc = gpre;   // h(-1) = 0
        }

#pragma unroll
        for (int q = 0; q < 4; q++) gl[(4 * hi4 + q) * 17 + b] = acc[q];
        __syncthreads();

        const int jj = hi4;
        float gi = gl[( 0 + jj) * 17 + b];
        float gf = gl[( 4 + jj) * 17 + b];
        float gg = gl[( 8 + jj) * 17 + b];
        float go = gl[(12 + jj) * 17 + b];
        __syncthreads();

        float si = 1.f / (1.f + expf(-gi));
        float sf = 1.f / (1.f + expf(-gf));
        float tg = tanhf(gg);
        float so = 1.f / (1.f + expf(-go));
        float c  = sf * c_reg + si * tg;
        c_reg = c;
        float h  = so * tanhf(c);

        // publish FIRST (critical path), hbuf store after (consumed next dispatch)
        if (s < SS - 1) {
            _Float16 hh = (_Float16)h;
            _Float16 hl = (_Float16)((h - (float)hh) * 2048.f);
            unsigned uh = __builtin_bit_cast(unsigned short, hh);
            unsigned ul = __builtin_bit_cast(unsigned short, hl);
            unsigned ph = uh | (((unsigned)__shfl_down((int)uh, 16)) << 16);
            unsigned pl = ul | (((unsigned)__shfl_down((int)ul, 16)) << 16);
            if ((jj & 1) == 0) {
                int k0 = j0 + jj;
                int kt = k0 >> 5, ko = k0 & 31;
                int lg = ko >> 3, e = ko & 7;
                size_t u16idx = ((size_t)(s * 13 + kt) * 64 + (lg * 16 + b)) * 8 + e;
                __hip_atomic_store((unsigned*)(exh_d + u16idx), ph,
                                   __ATOMIC_RELAXED, __HIP_MEMORY_SCOPE_AGENT);
                __hip_atomic_store((unsigned*)(exl_d + u16idx), pl,
                                   __ATOMIC_RELAXED, __HIP_MEMORY_SCOPE_AGENT);
            }
            // no vmcnt wait, no counter: validity is in-band (poison scheme)
        }

        hbuf[(size_t)(b * SS + time) * H2 + dir * HH + j0 + jj] = h;
    }
}

// ---------------- attention scores ----------------
#define ITILE 11
__global__ __launch_bounds__(256) void attn_scores_kernel(
    const float* __restrict__ ua, const float* __restrict__ wa,
    const float* __restrict__ va, float* __restrict__ scores)
{
    int b  = blockIdx.x / 9;
    int i0 = (blockIdx.x % 9) * ITILE;
    int tid = threadIdx.x;
    __shared__ float ua_t[100][101];
    __shared__ float wa_t[ITILE][102];
    __shared__ float sacc[ITILE][101];
    __shared__ float va_t[100];

    for (int p = tid; p < ITILE * 101; p += 256) ((float*)sacc)[p] = 0.f;

    for (int ht = 0; ht < 8; ht++) {
        int h0 = ht * 100;
        __syncthreads();
        for (int p = tid; p < 100 * 100; p += 256) {
            int j = p / 100, hh = p % 100;
            ua_t[j][hh] = ua[(size_t)(b * SS + j) * H2 + h0 + hh];
        }
        for (int p = tid; p < ITILE * 100; p += 256) {
            int il = p / 100, hh = p % 100;
            wa_t[il][hh] = wa[(size_t)(b * SS + i0 + il + 1) * H2 + h0 + hh];
        }
        if (tid < 100) va_t[tid] = va[h0 + tid];
        __syncthreads();
        for (int p = tid; p < ITILE * 100; p += 256) {
            int il = p / 100, j = p % 100;
            float acc = 0.f;
#pragma unroll 4
            for (int hh = 0; hh < 100; hh++) {
                float x = ua_t[j][hh] + wa_t[il][hh];
                float z = __expf(2.f * x);
                float th = 1.f - 2.f * __builtin_amdgcn_rcpf(z + 1.f);
                acc = fmaf(th, va_t[hh], acc);
            }
            sacc[il][j] += acc;
        }
    }
    __syncthreads();
    for (int p = tid; p < ITILE * 100; p += 256) {
        int il = p / 100, j = p % 100;
        scores[(size_t)(b * 99 + i0 + il) * 100 + j] = sacc[il][j];
    }
}

// ---------------- softmax / table / preds / nll per (b,i) row ----------------
__global__ __launch_bounds__(128) void attn_softmax_kernel(
    const float* __restrict__ scores, const float* __restrict__ out2,
    const int* __restrict__ head, float* __restrict__ outb,
    float* __restrict__ nll)
{
    int bi = blockIdx.x;           // b*99 + i
    int b = bi / 99, i = bi % 99;
    int j = threadIdx.x;
    __shared__ float sv[128];
    __shared__ int   si[128];
    __shared__ float red[128];

    float h_t = out2[(size_t)(b * SS + i + 1) * H2];
    float sj = -1e30f;
    if (j < 100) {
        sj = scores[(size_t)bi * 100 + j];
        float h_j = out2[(size_t)(b * SS + j) * H2];
        if (h_j == h_t) sj = -10000.0f;
    }
    sv[j] = sj; si[j] = j;
    __syncthreads();
    for (int off = 64; off >= 1; off >>= 1) {
        if (j < off) {
            float o = sv[j + off]; int oi = si[j + off];
            if (o > sv[j] || (o == sv[j] && oi < si[j])) { sv[j] = o; si[j] = oi; }
        }
        __syncthreads();
    }
    float m = sv[0]; int amax = si[0];
    __syncthreads();
    float e = (j < 100) ? __expf(sj - m) : 0.f;
    red[j] = e;
    __syncthreads();
    for (int off = 64; off >= 1; off >>= 1) {
        if (j < off) red[j] += red[j + off];
        __syncthreads();
    }
    float sum = red[0];
    float inv = 1.f / sum;
    if (j < 100) outb[1 + 1584 + (size_t)bi * 100 + j] = e * inv;
    if (j == 0) {
        outb[1 + bi] = (float)amax;
        int gold = head[b * SS + i + 1];
        bool valid = (gold != -1);
        int gc = gold < 0 ? 0 : (gold > 99 ? 99 : gold);
        float sgc = scores[(size_t)bi * 100 + gc];
        float hgc = out2[(size_t)(b * SS + gc) * H2];
        if (hgc == h_t) sgc = -10000.0f;
        nll[bi] = valid ? -(sgc - m - logf(sum)) : 0.f;
    }
}

// ---------------- final loss reduction ----------------
__global__ __launch_bounds__(128) void loss_kernel(
    const float* __restrict__ nll, const int* __restrict__ head,
    float* __restrict__ outb)
{
    __shared__ float red[128];
    int tid = threadIdx.x;
    float contrib = 0.f;
    if (tid < 99) {
        int i = tid;
        float tot = 0.f; int cv = 0;
        for (int b = 0; b < BB; b++) {
            tot += nll[b * 99 + i];
            cv += (head[b * SS + i + 1] != -1) ? 1 : 0;
        }
        int denom = cv > 0 ? cv : 1;
        contrib = tot / (float)denom;
    }
    red[tid] = contrib;
    __syncthreads();
    for (int off = 64; off >= 1; off >>= 1) {
        if (tid < off) red[tid] += red[tid + off];
        __syncthreads();
    }
    if (tid == 0) outb[0] = red[0];
}

// ---------------- launch ----------------
extern "C" void kernel_launch(void* const* d_in, const int* in_sizes, int n_in,
                              void* d_out, int out_size, void* d_ws, size_t ws_size,
                              hipStream_t stream) {
    const int*   tok     = (const int*)d_in[0];
    const int*   pos     = (const int*)d_in[1];
    const int*   head    = (const int*)d_in[2];
    const float* word_W  = (const float*)d_in[3];
    const float* pos_W   = (const float*)d_in[4];
    const float* l0f_Wih = (const float*)d_in[5];
    const float* l0f_Whh = (const float*)d_in[6];
    const float* l0f_b   = (const float*)d_in[7];
    const float* l0b_Wih = (const float*)d_in[8];
    const float* l0b_Whh = (const float*)d_in[9];
    const float* l0b_b   = (const float*)d_in[10];
    const float* l1f_Wih = (const float*)d_in[11];
    const float* l1f_Whh = (const float*)d_in[12];
    const float* l1f_b   = (const float*)d_in[13];
    const float* l1b_Wih = (const float*)d_in[14];
    const float* l1b_Whh = (const float*)d_in[15];
    const float* l1b_b   = (const float*)d_in[16];
    const float* ua_W    = (const float*)d_in[17];
    const float* ua_b    = (const float*)d_in[18];
    const float* wa_W    = (const float*)d_in[19];
    const float* wa_b    = (const float*)d_in[20];
    const float* va_W    = (const float*)d_in[21];

    float* ws   = (float*)d_ws;
    float* gf   = ws + OFF_GF;   // g0f / g1f / ua
    float* gb   = ws + OFF_GB;   // g0b / g1b / wa
    float* h1   = ws + OFF_H1;
    float* out2 = ws + OFF_OUT2; // also x0p/wfp/wbp staging before layer-1 LSTM
    float* sc   = ws + OFF_SC;
    float* nllb = ws + OFF_NLL;
    unsigned short* exhi = (unsigned short*)(ws + OFF_EXH);
    unsigned short* exlo = exhi + EX_U16_PER_PLANE;
    float* outf = (float*)d_out;

    // poison both exchange planes (0xFF per byte -> 0xFFFFFFFF per u32)
    hipMemsetAsync(exhi, 0xFF, 2 * EX_U16_PER_PLANE * sizeof(unsigned short), stream);

    // embedding (K=160-padded) + zero-padded layer-0 Wih copies, staged in OUT2
    embed_pad_kernel<<<dim3((3 * 1600 * KP0 + 255) / 256), 256, 0, stream>>>(
        tok, pos, word_W, pos_W, l0f_Wih, l0b_Wih, out2);

    float* x0p = out2 + PAD_X0;
    float* wfp = out2 + PAD_WF;
    float* wbp = out2 + PAD_WB;

    // layer-0 input projections (MFMA, K=160, fused f+b)
    gemm_nt_mfma_dual<<<dim3(50, 25), 256, 0, stream>>>(
        x0p, wfp, l0f_b, gf, wbp, l0b_b, gb, 1600, KP0, G4, nullptr, 0);
    // layer-0 recurrence (consumes initial poison)
    lstm_layer_kernel<<<dim3(200), 64, 0, stream>>>(
        gf, gb, l0f_Whh, l0b_Whh, h1, exhi, exlo);
    // layer-1 input projections (MFMA, K=800, fused f+b) + exchange RE-POISON
    gemm_nt_mfma_dual<<<dim3(50, 25), 256, 0, stream>>>(
        h1, l1f_Wih, l1f_b, gf, l1b_Wih, l1b_b, gb, 1600, H2, G4,
        (unsigned int*)exhi, (int)EX_U16_PER_PLANE);   // 2 planes * 2B / 4B = EX_U16 u32s
    // layer-1 recurrence (overwrites the x0p/wfp/wbp staging -- by now unused)
    lstm_layer_kernel<<<dim3(200), 64, 0, stream>>>(
        gf, gb, l1f_Whh, l1b_Whh, out2, exhi, exlo);
    // attention projections (MFMA, K=800, R=800, fused ua+wa)
    gemm_nt_mfma_dual<<<dim3(26, 25), 256, 0, stream>>>(
        out2, ua_W, ua_b, gf, wa_W, wa_b, gb, 1600, H2, H2, nullptr, 0);
    // scores, softmax/table/preds/nll, loss
    attn_scores_kernel<<<dim3(16 * 9), 256, 0, stream>>>(gf, gb, va_W, sc);
    attn_softmax_kernel<<<dim3(1584), 128, 0, stream>>>(sc, out2, head, outf, nllb);
    loss_kernel<<<dim3(1), 128, 0, stream>>>(nllb, head, outf);
}

// Round 10
// 1435.429 us; speedup vs baseline: 1.4914x; 1.0035x over previous
//
#include <hip/hip_runtime.h>

// ---------------- problem constants ----------------
#define BB 16
#define SS 100
#define HH 400      // hidden per direction
#define H2 800
#define G4 1600     // 4*H gate rows
#define DIN0 150    // WE+PE
#define KP0 160     // padded layer-0 K (150 -> 160, K%32==0)

// ---------------- workspace layout (float offsets) ----------------
#define OFF_GF   240000ULL     // 2,560,000 (g0f / g1f / ua)
#define OFF_GB   2800000ULL    // 2,560,000 (g0b / g1b / wa)
#define OFF_H1   5360000ULL    // 1,280,000
#define OFF_OUT2 6640000ULL    // 1,280,000
#define OFF_NLL  8078400ULL    // 1,600
#define OFF_EXH  8081600ULL    // u16 exchange planes (exhi then exlo, contiguous)
#define EX_U16_PER_PLANE 1331200ULL   // 2 dir * 100 steps * 13 kt * 64 * 8

typedef _Float16 f16x8 __attribute__((ext_vector_type(8)));
typedef float    f32x4 __attribute__((ext_vector_type(4)));
typedef unsigned long long u64x2 __attribute__((ext_vector_type(2)));

// poison check: u32 half == 0xFFFFFFFF (two f16 NaNs -- unreachable by real data)
static __device__ __forceinline__ unsigned chkp(unsigned long long q) {
    return ((unsigned)q == 0xFFFFFFFFu) | ((unsigned)(q >> 32) == 0xFFFFFFFFu);
}
// zero any poison halves (rail: turns a liveness bug into bounded error)
static __device__ __forceinline__ unsigned long long sanq(unsigned long long q) {
    if ((unsigned)q == 0xFFFFFFFFu)         q &= 0xFFFFFFFF00000000ull;
    if ((unsigned)(q >> 32) == 0xFFFFFFFFu) q &= 0x00000000FFFFFFFFull;
    return q;
}

// ---------------- f32 -> f16 hi/lo conversion (8 elems) ----------------
static __device__ __forceinline__ void cvt8(const float* v, f16x8& hi, f16x8& lo)
{
#pragma unroll
    for (int i = 0; i < 8; i++) {
        _Float16 h = (_Float16)v[i];
        hi[i] = h;
        lo[i] = (_Float16)((v[i] - (float)h) * 2048.f);
    }
}
static __device__ __forceinline__ void cvt_pair8(float4 a, float4 b,
                                                 f16x8& hi, f16x8& lo)
{
    float v[8] = {a.x, a.y, a.z, a.w, b.x, b.y, b.z, b.w};
    cvt8(v, hi, lo);
}

// ---------------- layer-0 dual GEMM with fused embedding + poison init ----------------
// A[r][k] computed on the fly: k<100 -> wW[tok[r]][k], k<150 -> pW[pos[r]][k-100], else 0.
// W rows read directly from l0*_Wih (row stride 150, scalar loads, k<150 guard).
// Prologue poisons both LSTM exchange planes (validated pattern: dispatch-boundary
// flush makes plain stores visible to the next dispatch's agent-scope atomic loads).
__global__ __launch_bounds__(256) void gemm_l0_embed_dual(
    const int* __restrict__ tok, const int* __restrict__ pos,
    const float* __restrict__ wW, const float* __restrict__ pW,
    const float* __restrict__ W0, const float* __restrict__ b0, float* __restrict__ C0,
    const float* __restrict__ W1, const float* __restrict__ b1, float* __restrict__ C1,
    unsigned int* __restrict__ poison, int poison_words)
{
    {
        int nthreads = gridDim.x * gridDim.y * 256;
        int gtid = (blockIdx.y * gridDim.x + blockIdx.x) * 256 + threadIdx.x;
        for (int i = gtid; i < poison_words; i += nthreads) poison[i] = 0xFFFFFFFFu;
    }

    int half = gridDim.x >> 1;
    int sel = blockIdx.x >= half;
    int bx = blockIdx.x - (sel ? half : 0);
    const float* W = sel ? W1 : W0;
    const float* bias = sel ? b1 : b0;
    float* C = sel ? C1 : C0;

    int tid = threadIdx.x;
    int wv = tid >> 6, l = tid & 63;
    int lm = l & 15, lk = l >> 4;
    int rs = bx * 64 + wv * 16;          // < 1600 always
    int n0 = blockIdx.y * 64;

    int trow[4], prow[4];
#pragma unroll
    for (int ct = 0; ct < 4; ct++) {
        int r = n0 + ct * 16 + lm;
        trow[ct] = tok[r];
        prow[ct] = pos[r];
    }
    const float* wrow = W + (size_t)(rs + lm) * DIN0;

    f32x4 accH[4], accX[4];
#pragma unroll
    for (int ct = 0; ct < 4; ct++) {
        accH[ct] = {0.f, 0.f, 0.f, 0.f};
        accX[ct] = {0.f, 0.f, 0.f, 0.f};
    }

#pragma unroll
    for (int kt = 0; kt < 5; kt++) {     // KP0=160 -> 5 k-tiles
        int kb = kt << 5;
        float wv8[8];
#pragma unroll
        for (int e = 0; e < 8; e++) {
            int k = kb + lk * 8 + e;
            wv8[e] = (k < DIN0) ? wrow[k] : 0.f;
        }
        f16x8 wh, wl;
        cvt8(wv8, wh, wl);
#pragma unroll
        for (int ct = 0; ct < 4; ct++) {
            float av8[8];
#pragma unroll
            for (int e = 0; e < 8; e++) {
                int k = kb + lk * 8 + e;
                float v = 0.f;
                if (k < 100)       v = wW[trow[ct] * 100 + k];
                else if (k < DIN0) v = pW[prow[ct] * 50 + (k - 100)];
                av8[e] = v;
            }
            f16x8 ah, al;
            cvt8(av8, ah, al);
            accH[ct] = __builtin_amdgcn_mfma_f32_16x16x32_f16(wh, ah, accH[ct], 0, 0, 0);
            accX[ct] = __builtin_amdgcn_mfma_f32_16x16x32_f16(wh, al, accX[ct], 0, 0, 0);
            accX[ct] = __builtin_amdgcn_mfma_f32_16x16x32_f16(wl, ah, accX[ct], 0, 0, 0);
        }
    }

    float4 bv = *(const float4*)&bias[rs + lk * 4];
#pragma unroll
    for (int ct = 0; ct < 4; ct++) {
        f32x4 v = accH[ct] + accX[ct] * (1.f / 2048.f);
        float4 o;
        o.x = v[0] + bv.x; o.y = v[1] + bv.y; o.z = v[2] + bv.z; o.w = v[3] + bv.w;
        *(float4*)&C[(size_t)(n0 + ct * 16 + lm) * G4 + rs + lk * 4] = o;
    }
}

// ---------------- dual MFMA NT GEMM (+ optional exchange re-poison) ----------------
__global__ __launch_bounds__(256) void gemm_nt_mfma_dual(
    const float* __restrict__ A,
    const float* __restrict__ W0, const float* __restrict__ b0, float* __restrict__ C0,
    const float* __restrict__ W1, const float* __restrict__ b1, float* __restrict__ C1,
    int N, int K, int R,
    unsigned int* __restrict__ poison, int poison_words)
{
    if (poison) {
        int nthreads = gridDim.x * gridDim.y * 256;
        int gtid = (blockIdx.y * gridDim.x + blockIdx.x) * 256 + threadIdx.x;
        for (int i = gtid; i < poison_words; i += nthreads) poison[i] = 0xFFFFFFFFu;
    }

    int half = gridDim.x >> 1;
    int sel = blockIdx.x >= half;
    int bx = blockIdx.x - (sel ? half : 0);
    const float* W = sel ? W1 : W0;
    const float* bias = sel ? b1 : b0;
    float* C = sel ? C1 : C0;

    int tid = threadIdx.x;
    int wv = tid >> 6, l = tid & 63;
    int lm = l & 15, lk = l >> 4;
    int rs = bx * 64 + wv * 16;
    if (rs >= R) return;
    int n0 = blockIdx.y * 64;

    const float* wrow = W + (size_t)(rs + lm) * K + lk * 8;
    const float* arow = A + (size_t)(n0 + lm) * K + lk * 8;

    f32x4 accH[4], accX[4];
#pragma unroll
    for (int ct = 0; ct < 4; ct++) {
        accH[ct] = {0.f, 0.f, 0.f, 0.f};
        accX[ct] = {0.f, 0.f, 0.f, 0.f};
    }

    int ksteps = K >> 5;
    for (int kt = 0; kt < ksteps; kt++) {
        int kb = kt << 5;
        float4 wlo4 = *(const float4*)(wrow + kb);
        float4 whi4 = *(const float4*)(wrow + kb + 4);
        f16x8 wh, wl;
        cvt_pair8(wlo4, whi4, wh, wl);
#pragma unroll
        for (int ct = 0; ct < 4; ct++) {
            const float* ap = arow + (size_t)(ct * 16) * K + kb;
            float4 aa = *(const float4*)ap;
            float4 ab = *(const float4*)(ap + 4);
            f16x8 ah, al;
            cvt_pair8(aa, ab, ah, al);
            accH[ct] = __builtin_amdgcn_mfma_f32_16x16x32_f16(wh, ah, accH[ct], 0, 0, 0);
            accX[ct] = __builtin_amdgcn_mfma_f32_16x16x32_f16(wh, al, accX[ct], 0, 0, 0);
            accX[ct] = __builtin_amdgcn_mfma_f32_16x16x32_f16(wl, ah, accX[ct], 0, 0, 0);
        }
    }

    float4 bv = *(const float4*)&bias[rs + lk * 4];
#pragma unroll
    for (int ct = 0; ct < 4; ct++) {
        f32x4 v = accH[ct] + accX[ct] * (1.f / 2048.f);
        float4 o;
        o.x = v[0] + bv.x; o.y = v[1] + bv.y; o.z = v[2] + bv.z; o.w = v[3] + bv.w;
        *(float4*)&C[(size_t)(n0 + ct * 16 + lm) * R + rs + lk * 4] = o;
    }
}

// ---------------- LSTM recurrence: MFMA f16 hi/lo, in-band poison sync ----------------
// (round-9 verified version, ~453 us/dispatch -- DO NOT TOUCH, control)
__global__ __launch_bounds__(64, 1) void lstm_layer_kernel(
    const float* __restrict__ Gf, const float* __restrict__ Gb,
    const float* __restrict__ Wf, const float* __restrict__ Wb,
    float* __restrict__ hbuf,          // [B][S][800] fp32 for downstream kernels
    unsigned short* __restrict__ exhi, // f16 hi plane, frag layout [dir][s][kt][64][8]
    unsigned short* __restrict__ exlo) // f16 lo plane (x2048)
{
    const int dir = blockIdx.x / 100;
    const int wg  = blockIdx.x % 100;
    const int j0  = wg * 4;
    const float* __restrict__ G = dir ? Gb : Gf;
    const float* __restrict__ W = dir ? Wb : Wf;

    const int l   = threadIdx.x;   // 0..63
    const int b   = l & 15;
    const int hi4 = l >> 4;

    __shared__ __attribute__((aligned(16))) unsigned short ahi[13 * 64 * 8];
    __shared__ __attribute__((aligned(16))) unsigned short alo[13 * 64 * 8];
    __shared__ float gl[16 * 17];

    {
        const int m = b;
        const int g = m >> 2, jj = m & 3;
        const float* wrow = W + (size_t)(g * HH + j0 + jj) * HH;
        for (int kt = 0; kt < 13; kt++) {
            for (int e = 0; e < 8; e++) {
                int k = kt * 32 + hi4 * 8 + e;
                float w = (k < HH) ? wrow[k] : 0.f;
                _Float16 wh = (_Float16)w;
                _Float16 wl = (_Float16)((w - (float)wh) * 2048.f);
                ahi[(kt * 64 + l) * 8 + e] = __builtin_bit_cast(unsigned short, wh);
                alo[(kt * 64 + l) * 8 + e] = __builtin_bit_cast(unsigned short, wl);
            }
        }
    }
    __syncthreads();

    float c_reg = 0.f;
    unsigned short* exh_d = exhi + (size_t)dir * 100 * 13 * 512;
    unsigned short* exl_d = exlo + (size_t)dir * 100 * 13 * 512;
    const int pad_lane = (hi4 >= 2);   // kt=12 k-range 400..415 for this lane

    for (int s = 0; s < SS; s++) {
        const int time = dir ? (SS - 1 - s) : s;
        f32x4 gpre = *(const f32x4*)&G[(size_t)(b * SS + time) * G4 + hi4 * HH + j0];

        f32x4 acc;
        if (s > 0) {
            const unsigned long long* pbh =
                (const unsigned long long*)(exh_d + (size_t)(s - 1) * 13 * 512);
            const unsigned long long* pbl =
                (const unsigned long long*)(exl_d + (size_t)(s - 1) * 13 * 512);
            u64x2 vh2[13], vl2[13];
            vh2[12] = {0ull, 0ull};
            vl2[12] = {0ull, 0ull};
            unsigned bad = 1;
            for (int guard = 0; guard < (1 << 13); guard++) {
                bad = 0;
#pragma unroll
                for (int kt = 0; kt < 12; kt++) {
                    size_t q = (size_t)(kt * 64 + l) * 2;
                    vh2[kt][0] = __hip_atomic_load(pbh + q,     __ATOMIC_RELAXED, __HIP_MEMORY_SCOPE_AGENT);
                    vh2[kt][1] = __hip_atomic_load(pbh + q + 1, __ATOMIC_RELAXED, __HIP_MEMORY_SCOPE_AGENT);
                    vl2[kt][0] = __hip_atomic_load(pbl + q,     __ATOMIC_RELAXED, __HIP_MEMORY_SCOPE_AGENT);
                    vl2[kt][1] = __hip_atomic_load(pbl + q + 1, __ATOMIC_RELAXED, __HIP_MEMORY_SCOPE_AGENT);
                }
                if (!pad_lane) {
                    size_t q = (size_t)(12 * 64 + l) * 2;
                    vh2[12][0] = __hip_atomic_load(pbh + q,     __ATOMIC_RELAXED, __HIP_MEMORY_SCOPE_AGENT);
                    vh2[12][1] = __hip_atomic_load(pbh + q + 1, __ATOMIC_RELAXED, __HIP_MEMORY_SCOPE_AGENT);
                    vl2[12][0] = __hip_atomic_load(pbl + q,     __ATOMIC_RELAXED, __HIP_MEMORY_SCOPE_AGENT);
                    vl2[12][1] = __hip_atomic_load(pbl + q + 1, __ATOMIC_RELAXED, __HIP_MEMORY_SCOPE_AGENT);
                    bad |= chkp(vh2[12][0]) | chkp(vh2[12][1])
                         | chkp(vl2[12][0]) | chkp(vl2[12][1]);
                }
#pragma unroll
                for (int kt = 0; kt < 12; kt++) {
                    bad |= chkp(vh2[kt][0]) | chkp(vh2[kt][1])
                         | chkp(vl2[kt][0]) | chkp(vl2[kt][1]);
                }
                if (__ballot(bad != 0) == 0ull) break;
                __builtin_amdgcn_s_sleep(2);
            }
            if (bad) {
#pragma unroll
                for (int kt = 0; kt < 13; kt++) {
                    vh2[kt][0] = sanq(vh2[kt][0]); vh2[kt][1] = sanq(vh2[kt][1]);
                    vl2[kt][0] = sanq(vl2[kt][0]); vl2[kt][1] = sanq(vl2[kt][1]);
                }
            }
            asm volatile("" ::: "memory");

            f32x4 aHH = gpre;
            f32x4 aHL = {0.f, 0.f, 0.f, 0.f};
            f32x4 aLH = {0.f, 0.f, 0.f, 0.f};
#pragma unroll
            for (int kt = 0; kt < 13; kt++) {
                f16x8 bhv = __builtin_bit_cast(f16x8, vh2[kt]);
                f16x8 blv = __builtin_bit_cast(f16x8, vl2[kt]);
                f16x8 wh = *(const f16x8*)&ahi[(kt * 64 + l) * 8];
                f16x8 wl = *(const f16x8*)&alo[(kt * 64 + l) * 8];
                aHH = __builtin_amdgcn_mfma_f32_16x16x32_f16(wh, bhv, aHH, 0, 0, 0);
                aHL = __builtin_amdgcn_mfma_f32_16x16x32_f16(wh, blv, aHL, 0, 0, 0);
                aLH = __builtin_amdgcn_mfma_f32_16x16x32_f16(wl, bhv, aLH, 0, 0, 0);
            }
            acc = aHH + (aHL + aLH) * (1.f / 2048.f);
        } else {
            acc = gpre;   // h(-1) = 0
        }

#pragma unroll
        for (int q = 0; q < 4; q++) gl[(4 * hi4 + q) * 17 + b] = acc[q];
        __syncthreads();

        const int jj = hi4;
        float gi = gl[( 0 + jj) * 17 + b];
        float gf = gl[( 4 + jj) * 17 + b];
        float gg = gl[( 8 + jj) * 17 + b];
        float go = gl[(12 + jj) * 17 + b];
        __syncthreads();

        float si = 1.f / (1.f + expf(-gi));
        float sf = 1.f / (1.f + expf(-gf));
        float tg = tanhf(gg);
        float so = 1.f / (1.f + expf(-go));
        float c  = sf * c_reg + si * tg;
        c_reg = c;
        float h  = so * tanhf(c);

        if (s < SS - 1) {
            _Float16 hh = (_Float16)h;
            _Float16 hl = (_Float16)((h - (float)hh) * 2048.f);
            unsigned uh = __builtin_bit_cast(unsigned short, hh);
            unsigned ul = __builtin_bit_cast(unsigned short, hl);
            unsigned ph = uh | (((unsigned)__shfl_down((int)uh, 16)) << 16);
            unsigned pl = ul | (((unsigned)__shfl_down((int)ul, 16)) << 16);
            if ((jj & 1) == 0) {
                int k0 = j0 + jj;
                int kt = k0 >> 5, ko = k0 & 31;
                int lg = ko >> 3, e = ko & 7;
                size_t u16idx = ((size_t)(s * 13 + kt) * 64 + (lg * 16 + b)) * 8 + e;
                __hip_atomic_store((unsigned*)(exh_d + u16idx), ph,
                                   __ATOMIC_RELAXED, __HIP_MEMORY_SCOPE_AGENT);
                __hip_atomic_store((unsigned*)(exl_d + u16idx), pl,
                                   __ATOMIC_RELAXED, __HIP_MEMORY_SCOPE_AGENT);
            }
        }

        hbuf[(size_t)(b * SS + time) * H2 + dir * HH + j0 + jj] = h;
    }
}

// ---------------- attention scores + fused row softmax/table/preds/nll ----------------
// Row (b,i)'s 100 scores are fully computed inside one block -> softmax fused here.
// One wave per row (rows il = wv, wv+4, wv+8), 64-lane shuffle reductions,
// smallest-index argmax tiebreak (matches jnp.argmax first-occurrence).
#define ITILE 11
__global__ __launch_bounds__(256) void attn_scores_softmax_kernel(
    const float* __restrict__ ua, const float* __restrict__ wa,
    const float* __restrict__ va, const float* __restrict__ out2,
    const int* __restrict__ head, float* __restrict__ outb,
    float* __restrict__ nll)
{
    int b  = blockIdx.x / 9;
    int i0 = (blockIdx.x % 9) * ITILE;
    int tid = threadIdx.x;
    __shared__ float ua_t[100][101];
    __shared__ float wa_t[ITILE][102];
    __shared__ float sacc[ITILE][101];
    __shared__ float va_t[100];
    __shared__ float h0[100];

    for (int p = tid; p < ITILE * 101; p += 256) ((float*)sacc)[p] = 0.f;
    if (tid < 100) h0[tid] = out2[(size_t)(b * SS + tid) * H2];

    for (int ht = 0; ht < 8; ht++) {
        int hh0 = ht * 100;
        __syncthreads();
        for (int p = tid; p < 100 * 100; p += 256) {
            int j = p / 100, hh = p % 100;
            ua_t[j][hh] = ua[(size_t)(b * SS + j) * H2 + hh0 + hh];
        }
        for (int p = tid; p < ITILE * 100; p += 256) {
            int il = p / 100, hh = p % 100;
            wa_t[il][hh] = wa[(size_t)(b * SS + i0 + il + 1) * H2 + hh0 + hh];
        }
        if (tid < 100) va_t[tid] = va[hh0 + tid];
        __syncthreads();
        for (int p = tid; p < ITILE * 100; p += 256) {
            int il = p / 100, j = p % 100;
            float acc = 0.f;
#pragma unroll 4
            for (int hh = 0; hh < 100; hh++) {
                float x = ua_t[j][hh] + wa_t[il][hh];
                float z = __expf(2.f * x);
                float th = 1.f - 2.f * __builtin_amdgcn_rcpf(z + 1.f);
                acc = fmaf(th, va_t[hh], acc);
            }
            sacc[il][j] += acc;
        }
    }
    __syncthreads();

    // fused softmax: wave wv owns rows il = wv, wv+4, wv+8
    int wv = tid >> 6, ln = tid & 63;
    for (int il = wv; il < ITILE; il += 4) {
        int i = i0 + il;                 // 0..98
        int bi = b * 99 + i;
        float h_t = h0[i + 1];
        int j1 = ln, j2 = ln + 64;
        float s1 = sacc[il][j1];
        if (h0[j1] == h_t) s1 = -10000.0f;
        float s2 = -1e30f;
        if (j2 < 100) {
            s2 = sacc[il][j2];
            if (h0[j2] == h_t) s2 = -10000.0f;
        }
        float v = s1; int vi = j1;
        if (s2 > v) { v = s2; vi = j2; }          // j1 < j2: ties keep j1
        for (int k = 32; k >= 1; k >>= 1) {
            float vo = __shfl_xor(v, k);
            int   io = __shfl_xor(vi, k);
            if (vo > v || (vo == v && io < vi)) { v = vo; vi = io; }
        }
        float m = v; int amax = vi;
        float e1 = __expf(s1 - m);
        float e2 = (j2 < 100) ? __expf(s2 - m) : 0.f;
        float sum = e1 + e2;
        for (int k = 32; k >= 1; k >>= 1) sum += __shfl_xor(sum, k);
        float inv = 1.f / sum;
        outb[1 + 1584 + (size_t)bi * 100 + j1] = e1 * inv;
        if (j2 < 100) outb[1 + 1584 + (size_t)bi * 100 + j2] = e2 * inv;
        if (ln == 0) {
            outb[1 + bi] = (float)amax;
            int gold = head[b * SS + i + 1];
            bool valid = (gold != -1);
            int gc = gold < 0 ? 0 : (gold > 99 ? 99 : gold);
            float sgc = sacc[il][gc];
            if (h0[gc] == h_t) sgc = -10000.0f;
            nll[bi] = valid ? -(sgc - m - logf(sum)) : 0.f;
        }
    }
}

// ---------------- final loss reduction ----------------
__global__ __launch_bounds__(128) void loss_kernel(
    const float* __restrict__ nll, const int* __restrict__ head,
    float* __restrict__ outb)
{
    __shared__ float red[128];
    int tid = threadIdx.x;
    float contrib = 0.f;
    if (tid < 99) {
        int i = tid;
        float tot = 0.f; int cv = 0;
        for (int b = 0; b < BB; b++) {
            tot += nll[b * 99 + i];
            cv += (head[b * SS + i + 1] != -1) ? 1 : 0;
        }
        int denom = cv > 0 ? cv : 1;
        contrib = tot / (float)denom;
    }
    red[tid] = contrib;
    __syncthreads();
    for (int off = 64; off >= 1; off >>= 1) {
        if (tid < off) red[tid] += red[tid + off];
        __syncthreads();
    }
    if (tid == 0) outb[0] = red[0];
}

// ---------------- launch (7 nodes) ----------------
extern "C" void kernel_launch(void* const* d_in, const int* in_sizes, int n_in,
                              void* d_out, int out_size, void* d_ws, size_t ws_size,
                              hipStream_t stream) {
    const int*   tok     = (const int*)d_in[0];
    const int*   pos     = (const int*)d_in[1];
    const int*   head    = (const int*)d_in[2];
    const float* word_W  = (const float*)d_in[3];
    const float* pos_W   = (const float*)d_in[4];
    const float* l0f_Wih = (const float*)d_in[5];
    const float* l0f_Whh = (const float*)d_in[6];
    const float* l0f_b   = (const float*)d_in[7];
    const float* l0b_Wih = (const float*)d_in[8];
    const float* l0b_Whh = (const float*)d_in[9];
    const float* l0b_b   = (const float*)d_in[10];
    const float* l1f_Wih = (const float*)d_in[11];
    const float* l1f_Whh = (const float*)d_in[12];
    const float* l1f_b   = (const float*)d_in[13];
    const float* l1b_Wih = (const float*)d_in[14];
    const float* l1b_Whh = (const float*)d_in[15];
    const float* l1b_b   = (const float*)d_in[16];
    const float* ua_W    = (const float*)d_in[17];
    const float* ua_b    = (const float*)d_in[18];
    const float* wa_W    = (const float*)d_in[19];
    const float* wa_b    = (const float*)d_in[20];
    const float* va_W    = (const float*)d_in[21];

    float* ws   = (float*)d_ws;
    float* gf   = ws + OFF_GF;   // g0f / g1f / ua
    float* gb   = ws + OFF_GB;   // g0b / g1b / wa
    float* h1   = ws + OFF_H1;
    float* out2 = ws + OFF_OUT2;
    float* nllb = ws + OFF_NLL;
    unsigned short* exhi = (unsigned short*)(ws + OFF_EXH);
    unsigned short* exlo = exhi + EX_U16_PER_PLANE;
    float* outf = (float*)d_out;

    // layer-0 projections: fused embedding + raw Wih (K=150 guard) + poison init
    gemm_l0_embed_dual<<<dim3(50, 25), 256, 0, stream>>>(
        tok, pos, word_W, pos_W,
        l0f_Wih, l0f_b, gf, l0b_Wih, l0b_b, gb,
        (unsigned int*)exhi, (int)EX_U16_PER_PLANE);
    // layer-0 recurrence
    lstm_layer_kernel<<<dim3(200), 64, 0, stream>>>(
        gf, gb, l0f_Whh, l0b_Whh, h1, exhi, exlo);
    // layer-1 projections (K=800) + exchange re-poison
    gemm_nt_mfma_dual<<<dim3(50, 25), 256, 0, stream>>>(
        h1, l1f_Wih, l1f_b, gf, l1b_Wih, l1b_b, gb, 1600, H2, G4,
        (unsigned int*)exhi, (int)EX_U16_PER_PLANE);
    // layer-1 recurrence
    lstm_layer_kernel<<<dim3(200), 64, 0, stream>>>(
        gf, gb, l1f_Whh, l1b_Whh, out2, exhi, exlo);
    // attention projections (K=800, R=800)
    gemm_nt_mfma_dual<<<dim3(26, 25), 256, 0, stream>>>(
        out2, ua_W, ua_b, gf, wa_W, wa_b, gb, 1600, H2, H2, nullptr, 0);
    // scores + fused softmax/table/preds/nll
    attn_scores_softmax_kernel<<<dim3(16 * 9), 256, 0, stream>>>(
        gf, gb, va_W, out2, head, outf, nllb);
    // final loss
    loss_kernel<<<dim3(1), 128, 0, stream>>>(nllb, head, outf);
}

// Round 11
// 1276.423 us; speedup vs baseline: 1.6772x; 1.1246x over previous
//
#include <hip/hip_runtime.h>

// ---------------- problem constants ----------------
#define BB 16
#define SS 100
#define HH 400      // hidden per direction
#define H2 800
#define G4 1600     // 4*H gate rows
#define DIN0 150    // WE+PE
#define KP0 160     // padded layer-0 K (150 -> 160, K%32==0)

// ---------------- workspace layout (float offsets) ----------------
#define OFF_GF   240000ULL     // 2,560,000 (g0f / g1f / ua)
#define OFF_GB   2800000ULL    // 2,560,000 (g0b / g1b / wa)
#define OFF_H1   5360000ULL    // 1,280,000
#define OFF_OUT2 6640000ULL    // 1,280,000
#define OFF_NLL  8078400ULL    // 1,600
#define OFF_EXH  8081600ULL    // u16 exchange planes (exhi then exlo, contiguous)
#define EX_U16_PER_PLANE 1331200ULL   // 2 dir * 100 steps * 13 kt * 64 * 8

typedef _Float16 f16x8 __attribute__((ext_vector_type(8)));
typedef float    f32x4 __attribute__((ext_vector_type(4)));
typedef unsigned long long u64x2 __attribute__((ext_vector_type(2)));

// poison check: u32 half == 0xFFFFFFFF (two f16 NaNs -- unreachable by real data)
static __device__ __forceinline__ unsigned chkp(unsigned long long q) {
    return ((unsigned)q == 0xFFFFFFFFu) | ((unsigned)(q >> 32) == 0xFFFFFFFFu);
}
// zero any poison halves (rail: turns a liveness bug into bounded error)
static __device__ __forceinline__ unsigned long long sanq(unsigned long long q) {
    if ((unsigned)q == 0xFFFFFFFFu)         q &= 0xFFFFFFFF00000000ull;
    if ((unsigned)(q >> 32) == 0xFFFFFFFFu) q &= 0x00000000FFFFFFFFull;
    return q;
}

// ---------------- f32 -> f16 hi/lo conversion (8 elems) ----------------
static __device__ __forceinline__ void cvt8(const float* v, f16x8& hi, f16x8& lo)
{
#pragma unroll
    for (int i = 0; i < 8; i++) {
        _Float16 h = (_Float16)v[i];
        hi[i] = h;
        lo[i] = (_Float16)((v[i] - (float)h) * 2048.f);
    }
}
static __device__ __forceinline__ void cvt_pair8(float4 a, float4 b,
                                                 f16x8& hi, f16x8& lo)
{
    float v[8] = {a.x, a.y, a.z, a.w, b.x, b.y, b.z, b.w};
    cvt8(v, hi, lo);
}

// LDS A-tile: [2 bufs][64 rows][40 u16] per plane (row stride 80 B -> frag reads
// are 2-way bank-aliased = free). Fragment (row, k0) = 16 B at row*40 + k0.
#define AROW 40

// ---------------- layer-0 dual GEMM: fused embedding, LDS-staged A, poison init ----------------
// A[r][k] built on the fly (tok/pos gather), staged ONCE per block into LDS as
// f16 hi/lo fragments shared by all 4 waves (was 4x redundant per-wave gathers).
__global__ __launch_bounds__(256) void gemm_l0_embed_dual(
    const int* __restrict__ tok, const int* __restrict__ pos,
    const float* __restrict__ wW, const float* __restrict__ pW,
    const float* __restrict__ W0, const float* __restrict__ b0, float* __restrict__ C0,
    const float* __restrict__ W1, const float* __restrict__ b1, float* __restrict__ C1,
    unsigned int* __restrict__ poison, int poison_words)
{
    {
        int nthreads = gridDim.x * gridDim.y * 256;
        int gtid = (blockIdx.y * gridDim.x + blockIdx.x) * 256 + threadIdx.x;
        for (int i = gtid; i < poison_words; i += nthreads) poison[i] = 0xFFFFFFFFu;
    }

    int half = gridDim.x >> 1;
    int sel = blockIdx.x >= half;
    int bx = blockIdx.x - (sel ? half : 0);
    const float* W = sel ? W1 : W0;
    const float* bias = sel ? b1 : b0;
    float* C = sel ? C1 : C0;

    int tid = threadIdx.x;
    int wv = tid >> 6, l = tid & 63;
    int lm = l & 15, lk = l >> 4;
    int rs = bx * 64 + wv * 16;          // < 1600 always
    int n0 = blockIdx.y * 64;

    __shared__ __attribute__((aligned(16))) unsigned short AhiS[2][64 * AROW];
    __shared__ __attribute__((aligned(16))) unsigned short AloS[2][64 * AROW];

    // staging role: thread -> (row sr, k-offset sc) of the 64x32 slice
    int sr = tid >> 2, sc = (tid & 3) * 8;
    int t_ = tok[n0 + sr], p_ = pos[n0 + sr];

    const float* wrow = W + (size_t)(rs + lm) * DIN0;

    f32x4 accH[4], accX[4];
#pragma unroll
    for (int ct = 0; ct < 4; ct++) {
        accH[ct] = {0.f, 0.f, 0.f, 0.f};
        accX[ct] = {0.f, 0.f, 0.f, 0.f};
    }

    // prologue: fetch + stage kt=0
    float a8[8];
#pragma unroll
    for (int e = 0; e < 8; e++) {
        int k = sc + e;
        a8[e] = (k < 100) ? wW[t_ * 100 + k]
              : (k < DIN0) ? pW[p_ * 50 + (k - 100)] : 0.f;
    }
    float w8[8];
#pragma unroll
    for (int e = 0; e < 8; e++) {
        int k = lk * 8 + e;
        w8[e] = (k < DIN0) ? wrow[k] : 0.f;
    }
    {
        f16x8 h, lo2; cvt8(a8, h, lo2);
        *(f16x8*)&AhiS[0][sr * AROW + sc] = h;
        *(f16x8*)&AloS[0][sr * AROW + sc] = lo2;
    }

    const int nkt = 5;                   // KP0 = 160
    for (int kt = 0; kt < nkt; kt++) {
        __syncthreads();                 // buf[kt&1] visible; prev reads done
        bool more = (kt + 1 < nkt);
        float a8n[8], w8n[8];
        if (more) {
            int kb = (kt + 1) << 5;
#pragma unroll
            for (int e = 0; e < 8; e++) {
                int k = kb + sc + e;
                a8n[e] = (k < 100) ? wW[t_ * 100 + k]
                       : (k < DIN0) ? pW[p_ * 50 + (k - 100)] : 0.f;
            }
#pragma unroll
            for (int e = 0; e < 8; e++) {
                int k = kb + lk * 8 + e;
                w8n[e] = (k < DIN0) ? wrow[k] : 0.f;
            }
        }
        f16x8 wh, wl; cvt8(w8, wh, wl);
        int buf = kt & 1;
#pragma unroll
        for (int ct = 0; ct < 4; ct++) {
            f16x8 ah = *(const f16x8*)&AhiS[buf][(ct * 16 + lm) * AROW + lk * 8];
            f16x8 al = *(const f16x8*)&AloS[buf][(ct * 16 + lm) * AROW + lk * 8];
            accH[ct] = __builtin_amdgcn_mfma_f32_16x16x32_f16(wh, ah, accH[ct], 0, 0, 0);
            accX[ct] = __builtin_amdgcn_mfma_f32_16x16x32_f16(wh, al, accX[ct], 0, 0, 0);
            accX[ct] = __builtin_amdgcn_mfma_f32_16x16x32_f16(wl, ah, accX[ct], 0, 0, 0);
        }
        if (more) {
            f16x8 h, lo2; cvt8(a8n, h, lo2);
            *(f16x8*)&AhiS[buf ^ 1][sr * AROW + sc] = h;
            *(f16x8*)&AloS[buf ^ 1][sr * AROW + sc] = lo2;
#pragma unroll
            for (int e = 0; e < 8; e++) w8[e] = w8n[e];
        }
    }

    float4 bv = *(const float4*)&bias[rs + lk * 4];
#pragma unroll
    for (int ct = 0; ct < 4; ct++) {
        f32x4 v = accH[ct] + accX[ct] * (1.f / 2048.f);
        float4 o;
        o.x = v[0] + bv.x; o.y = v[1] + bv.y; o.z = v[2] + bv.z; o.w = v[3] + bv.w;
        *(float4*)&C[(size_t)(n0 + ct * 16 + lm) * G4 + rs + lk * 4] = o;
    }
}

// ---------------- dual MFMA NT GEMM, LDS-staged shared A (+ optional re-poison) ----------------
// A-tile loaded+converted ONCE per block per k-slice (was 4x per-wave redundant),
// double-buffered in LDS, one barrier per k-tile, register prefetch of next slice.
// Ragged R edge: inactive waves keep staging + barriers, skip W/MFMA/store.
__global__ __launch_bounds__(256) void gemm_nt_mfma_dual(
    const float* __restrict__ A,
    const float* __restrict__ W0, const float* __restrict__ b0, float* __restrict__ C0,
    const float* __restrict__ W1, const float* __restrict__ b1, float* __restrict__ C1,
    int K, int R,
    unsigned int* __restrict__ poison, int poison_words)
{
    if (poison) {
        int nthreads = gridDim.x * gridDim.y * 256;
        int gtid = (blockIdx.y * gridDim.x + blockIdx.x) * 256 + threadIdx.x;
        for (int i = gtid; i < poison_words; i += nthreads) poison[i] = 0xFFFFFFFFu;
    }

    int half = gridDim.x >> 1;
    int sel = blockIdx.x >= half;
    int bx = blockIdx.x - (sel ? half : 0);
    const float* W = sel ? W1 : W0;
    const float* bias = sel ? b1 : b0;
    float* C = sel ? C1 : C0;

    int tid = threadIdx.x;
    int wv = tid >> 6, l = tid & 63;
    int lm = l & 15, lk = l >> 4;
    int rs = bx * 64 + wv * 16;
    bool active = (rs < R);
    int n0 = blockIdx.y * 64;

    __shared__ __attribute__((aligned(16))) unsigned short AhiS[2][64 * AROW];
    __shared__ __attribute__((aligned(16))) unsigned short AloS[2][64 * AROW];

    int sr = tid >> 2, sc = (tid & 3) * 8;
    const float* arow_g = A + (size_t)(n0 + sr) * K + sc;
    const float* wrow = W + (size_t)((active ? rs : 0) + lm) * K + lk * 8;

    f32x4 accH[4], accX[4];
#pragma unroll
    for (int ct = 0; ct < 4; ct++) {
        accH[ct] = {0.f, 0.f, 0.f, 0.f};
        accX[ct] = {0.f, 0.f, 0.f, 0.f};
    }

    // prologue: fetch + stage kt=0
    float a8[8];
    *(float4*)a8       = *(const float4*)arow_g;
    *(float4*)(a8 + 4) = *(const float4*)(arow_g + 4);
    float4 wA = {0,0,0,0}, wB = {0,0,0,0};
    if (active) { wA = *(const float4*)wrow; wB = *(const float4*)(wrow + 4); }
    {
        f16x8 h, lo2; cvt8(a8, h, lo2);
        *(f16x8*)&AhiS[0][sr * AROW + sc] = h;
        *(f16x8*)&AloS[0][sr * AROW + sc] = lo2;
    }

    int nkt = K >> 5;
    for (int kt = 0; kt < nkt; kt++) {
        __syncthreads();                 // buf[kt&1] visible; prev reads done
        bool more = (kt + 1 < nkt);
        float a8n[8]; float4 wAn = {0,0,0,0}, wBn = {0,0,0,0};
        if (more) {
            int kb = (kt + 1) << 5;
            *(float4*)a8n       = *(const float4*)(arow_g + kb);
            *(float4*)(a8n + 4) = *(const float4*)(arow_g + kb + 4);
            if (active) {
                wAn = *(const float4*)(wrow + kb);
                wBn = *(const float4*)(wrow + kb + 4);
            }
        }
        if (active) {
            f16x8 wh, wl; cvt_pair8(wA, wB, wh, wl);
            int buf = kt & 1;
#pragma unroll
            for (int ct = 0; ct < 4; ct++) {
                f16x8 ah = *(const f16x8*)&AhiS[buf][(ct * 16 + lm) * AROW + lk * 8];
                f16x8 al = *(const f16x8*)&AloS[buf][(ct * 16 + lm) * AROW + lk * 8];
                accH[ct] = __builtin_amdgcn_mfma_f32_16x16x32_f16(wh, ah, accH[ct], 0, 0, 0);
                accX[ct] = __builtin_amdgcn_mfma_f32_16x16x32_f16(wh, al, accX[ct], 0, 0, 0);
                accX[ct] = __builtin_amdgcn_mfma_f32_16x16x32_f16(wl, ah, accX[ct], 0, 0, 0);
            }
        }
        if (more) {
            f16x8 h, lo2; cvt8(a8n, h, lo2);
            *(f16x8*)&AhiS[(kt & 1) ^ 1][sr * AROW + sc] = h;
            *(f16x8*)&AloS[(kt & 1) ^ 1][sr * AROW + sc] = lo2;
            wA = wAn; wB = wBn;
        }
    }

    if (!active) return;
    float4 bv = *(const float4*)&bias[rs + lk * 4];
#pragma unroll
    for (int ct = 0; ct < 4; ct++) {
        f32x4 v = accH[ct] + accX[ct] * (1.f / 2048.f);
        float4 o;
        o.x = v[0] + bv.x; o.y = v[1] + bv.y; o.z = v[2] + bv.z; o.w = v[3] + bv.w;
        *(float4*)&C[(size_t)(n0 + ct * 16 + lm) * R + rs + lk * 4] = o;
    }
}

// ---------------- LSTM recurrence: MFMA f16 hi/lo, in-band poison sync ----------------
// (round-9 verified version, ~445 us/dispatch -- DO NOT TOUCH, control)
__global__ __launch_bounds__(64, 1) void lstm_layer_kernel(
    const float* __restrict__ Gf, const float* __restrict__ Gb,
    const float* __restrict__ Wf, const float* __restrict__ Wb,
    float* __restrict__ hbuf,          // [B][S][800] fp32 for downstream kernels
    unsigned short* __restrict__ exhi, // f16 hi plane, frag layout [dir][s][kt][64][8]
    unsigned short* __restrict__ exlo) // f16 lo plane (x2048)
{
    const int dir = blockIdx.x / 100;
    const int wg  = blockIdx.x % 100;
    const int j0  = wg * 4;
    const float* __restrict__ G = dir ? Gb : Gf;
    const float* __restrict__ W = dir ? Wb : Wf;

    const int l   = threadIdx.x;   // 0..63
    const int b   = l & 15;
    const int hi4 = l >> 4;

    __shared__ __attribute__((aligned(16))) unsigned short ahi[13 * 64 * 8];
    __shared__ __attribute__((aligned(16))) unsigned short alo[13 * 64 * 8];
    __shared__ float gl[16 * 17];

    {
        const int m = b;
        const int g = m >> 2, jj = m & 3;
        const float* wrow = W + (size_t)(g * HH + j0 + jj) * HH;
        for (int kt = 0; kt < 13; kt++) {
            for (int e = 0; e < 8; e++) {
                int k = kt * 32 + hi4 * 8 + e;
                float w = (k < HH) ? wrow[k] : 0.f;
                _Float16 wh = (_Float16)w;
                _Float16 wl = (_Float16)((w - (float)wh) * 2048.f);
                ahi[(kt * 64 + l) * 8 + e] = __builtin_bit_cast(unsigned short, wh);
                alo[(kt * 64 + l) * 8 + e] = __builtin_bit_cast(unsigned short, wl);
            }
        }
    }
    __syncthreads();

    float c_reg = 0.f;
    unsigned short* exh_d = exhi + (size_t)dir * 100 * 13 * 512;
    unsigned short* exl_d = exlo + (size_t)dir * 100 * 13 * 512;
    const int pad_lane = (hi4 >= 2);   // kt=12 k-range 400..415 for this lane

    for (int s = 0; s < SS; s++) {
        const int time = dir ? (SS - 1 - s) : s;
        f32x4 gpre = *(const f32x4*)&G[(size_t)(b * SS + time) * G4 + hi4 * HH + j0];

        f32x4 acc;
        if (s > 0) {
            const unsigned long long* pbh =
                (const unsigned long long*)(exh_d + (size_t)(s - 1) * 13 * 512);
            const unsigned long long* pbl =
                (const unsigned long long*)(exl_d + (size_t)(s - 1) * 13 * 512);
            u64x2 vh2[13], vl2[13];
            vh2[12] = {0ull, 0ull};
            vl2[12] = {0ull, 0ull};
            unsigned bad = 1;
            for (int guard = 0; guard < (1 << 13); guard++) {
                bad = 0;
#pragma unroll
                for (int kt = 0; kt < 12; kt++) {
                    size_t q = (size_t)(kt * 64 + l) * 2;
                    vh2[kt][0] = __hip_atomic_load(pbh + q,     __ATOMIC_RELAXED, __HIP_MEMORY_SCOPE_AGENT);
                    vh2[kt][1] = __hip_atomic_load(pbh + q + 1, __ATOMIC_RELAXED, __HIP_MEMORY_SCOPE_AGENT);
                    vl2[kt][0] = __hip_atomic_load(pbl + q,     __ATOMIC_RELAXED, __HIP_MEMORY_SCOPE_AGENT);
                    vl2[kt][1] = __hip_atomic_load(pbl + q + 1, __ATOMIC_RELAXED, __HIP_MEMORY_SCOPE_AGENT);
                }
                if (!pad_lane) {
                    size_t q = (size_t)(12 * 64 + l) * 2;
                    vh2[12][0] = __hip_atomic_load(pbh + q,     __ATOMIC_RELAXED, __HIP_MEMORY_SCOPE_AGENT);
                    vh2[12][1] = __hip_atomic_load(pbh + q + 1, __ATOMIC_RELAXED, __HIP_MEMORY_SCOPE_AGENT);
                    vl2[12][0] = __hip_atomic_load(pbl + q,     __ATOMIC_RELAXED, __HIP_MEMORY_SCOPE_AGENT);
                    vl2[12][1] = __hip_atomic_load(pbl + q + 1, __ATOMIC_RELAXED, __HIP_MEMORY_SCOPE_AGENT);
                    bad |= chkp(vh2[12][0]) | chkp(vh2[12][1])
                         | chkp(vl2[12][0]) | chkp(vl2[12][1]);
                }
#pragma unroll
                for (int kt = 0; kt < 12; kt++) {
                    bad |= chkp(vh2[kt][0]) | chkp(vh2[kt][1])
                         | chkp(vl2[kt][0]) | chkp(vl2[kt][1]);
                }
                if (__ballot(bad != 0) == 0ull) break;
                __builtin_amdgcn_s_sleep(2);
            }
            if (bad) {
#pragma unroll
                for (int kt = 0; kt < 13; kt++) {
                    vh2[kt][0] = sanq(vh2[kt][0]); vh2[kt][1] = sanq(vh2[kt][1]);
                    vl2[kt][0] = sanq(vl2[kt][0]); vl2[kt][1] = sanq(vl2[kt][1]);
                }
            }
            asm volatile("" ::: "memory");

            f32x4 aHH = gpre;
            f32x4 aHL = {0.f, 0.f, 0.f, 0.f};
            f32x4 aLH = {0.f, 0.f, 0.f, 0.f};
#pragma unroll
            for (int kt = 0; kt < 13; kt++) {
                f16x8 bhv = __builtin_bit_cast(f16x8, vh2[kt]);
                f16x8 blv = __builtin_bit_cast(f16x8, vl2[kt]);
                f16x8 wh = *(const f16x8*)&ahi[(kt * 64 + l) * 8];
                f16x8 wl = *(const f16x8*)&alo[(kt * 64 + l) * 8];
                aHH = __builtin_amdgcn_mfma_f32_16x16x32_f16(wh, bhv, aHH, 0, 0, 0);
                aHL = __builtin_amdgcn_mfma_f32_16x16x32_f16(wh, blv, aHL, 0, 0, 0);
                aLH = __builtin_amdgcn_mfma_f32_16x16x32_f16(wl, bhv, aLH, 0, 0, 0);
            }
            acc = aHH + (aHL + aLH) * (1.f / 2048.f);
        } else {
            acc = gpre;   // h(-1) = 0
        }

#pragma unroll
        for (int q = 0; q < 4; q++) gl[(4 * hi4 + q) * 17 + b] = acc[q];
        __syncthreads();

        const int jj = hi4;
        float gi = gl[( 0 + jj) * 17 + b];
        float gf = gl[( 4 + jj) * 17 + b];
        float gg = gl[( 8 + jj) * 17 + b];
        float go = gl[(12 + jj) * 17 + b];
        __syncthreads();

        float si = 1.f / (1.f + expf(-gi));
        float sf = 1.f / (1.f + expf(-gf));
        float tg = tanhf(gg);
        float so = 1.f / (1.f + expf(-go));
        float c  = sf * c_reg + si * tg;
        c_reg = c;
        float h  = so * tanhf(c);

        if (s < SS - 1) {
            _Float16 hh = (_Float16)h;
            _Float16 hl = (_Float16)((h - (float)hh) * 2048.f);
            unsigned uh = __builtin_bit_cast(unsigned short, hh);
            unsigned ul = __builtin_bit_cast(unsigned short, hl);
            unsigned ph = uh | (((unsigned)__shfl_down((int)uh, 16)) << 16);
            unsigned pl = ul | (((unsigned)__shfl_down((int)ul, 16)) << 16);
            if ((jj & 1) == 0) {
                int k0 = j0 + jj;
                int kt = k0 >> 5, ko = k0 & 31;
                int lg = ko >> 3, e = ko & 7;
                size_t u16idx = ((size_t)(s * 13 + kt) * 64 + (lg * 16 + b)) * 8 + e;
                __hip_atomic_store((unsigned*)(exh_d + u16idx), ph,
                                   __ATOMIC_RELAXED, __HIP_MEMORY_SCOPE_AGENT);
                __hip_atomic_store((unsigned*)(exl_d + u16idx), pl,
                                   __ATOMIC_RELAXED, __HIP_MEMORY_SCOPE_AGENT);
            }
        }

        hbuf[(size_t)(b * SS + time) * H2 + dir * HH + j0 + jj] = h;
    }
}

// ---------------- attention scores + fused row softmax/table/preds/nll ----------------
#define ITILE 11
__global__ __launch_bounds__(256) void attn_scores_softmax_kernel(
    const float* __restrict__ ua, const float* __restrict__ wa,
    const float* __restrict__ va, const float* __restrict__ out2,
    const int* __restrict__ head, float* __restrict__ outb,
    float* __restrict__ nll)
{
    int b  = blockIdx.x / 9;
    int i0 = (blockIdx.x % 9) * ITILE;
    int tid = threadIdx.x;
    __shared__ float ua_t[100][101];
    __shared__ float wa_t[ITILE][102];
    __shared__ float sacc[ITILE][101];
    __shared__ float va_t[100];
    __shared__ float h0[100];

    for (int p = tid; p < ITILE * 101; p += 256) ((float*)sacc)[p] = 0.f;
    if (tid < 100) h0[tid] = out2[(size_t)(b * SS + tid) * H2];

    for (int ht = 0; ht < 8; ht++) {
        int hh0 = ht * 100;
        __syncthreads();
        for (int p = tid; p < 100 * 100; p += 256) {
            int j = p / 100, hh = p % 100;
            ua_t[j][hh] = ua[(size_t)(b * SS + j) * H2 + hh0 + hh];
        }
        for (int p = tid; p < ITILE * 100; p += 256) {
            int il = p / 100, hh = p % 100;
            wa_t[il][hh] = wa[(size_t)(b * SS + i0 + il + 1) * H2 + hh0 + hh];
        }
        if (tid < 100) va_t[tid] = va[hh0 + tid];
        __syncthreads();
        for (int p = tid; p < ITILE * 100; p += 256) {
            int il = p / 100, j = p % 100;
            float acc = 0.f;
#pragma unroll 4
            for (int hh = 0; hh < 100; hh++) {
                float x = ua_t[j][hh] + wa_t[il][hh];
                float z = __expf(2.f * x);
                float th = 1.f - 2.f * __builtin_amdgcn_rcpf(z + 1.f);
                acc = fmaf(th, va_t[hh], acc);
            }
            sacc[il][j] += acc;
        }
    }
    __syncthreads();

    int wv = tid >> 6, ln = tid & 63;
    for (int il = wv; il < ITILE; il += 4) {
        int i = i0 + il;                 // 0..98
        int bi = b * 99 + i;
        float h_t = h0[i + 1];
        int j1 = ln, j2 = ln + 64;
        float s1 = sacc[il][j1];
        if (h0[j1] == h_t) s1 = -10000.0f;
        float s2 = -1e30f;
        if (j2 < 100) {
            s2 = sacc[il][j2];
            if (h0[j2] == h_t) s2 = -10000.0f;
        }
        float v = s1; int vi = j1;
        if (s2 > v) { v = s2; vi = j2; }          // j1 < j2: ties keep j1
        for (int k = 32; k >= 1; k >>= 1) {
            float vo = __shfl_xor(v, k);
            int   io = __shfl_xor(vi, k);
            if (vo > v || (vo == v && io < vi)) { v = vo; vi = io; }
        }
        float m = v; int amax = vi;
        float e1 = __expf(s1 - m);
        float e2 = (j2 < 100) ? __expf(s2 - m) : 0.f;
        float sum = e1 + e2;
        for (int k = 32; k >= 1; k >>= 1) sum += __shfl_xor(sum, k);
        float inv = 1.f / sum;
        outb[1 + 1584 + (size_t)bi * 100 + j1] = e1 * inv;
        if (j2 < 100) outb[1 + 1584 + (size_t)bi * 100 + j2] = e2 * inv;
        if (ln == 0) {
            outb[1 + bi] = (float)amax;
            int gold = head[b * SS + i + 1];
            bool valid = (gold != -1);
            int gc = gold < 0 ? 0 : (gold > 99 ? 99 : gold);
            float sgc = sacc[il][gc];
            if (h0[gc] == h_t) sgc = -10000.0f;
            nll[bi] = valid ? -(sgc - m - logf(sum)) : 0.f;
        }
    }
}

// ---------------- final loss reduction ----------------
__global__ __launch_bounds__(128) void loss_kernel(
    const float* __restrict__ nll, const int* __restrict__ head,
    float* __restrict__ outb)
{
    __shared__ float red[128];
    int tid = threadIdx.x;
    float contrib = 0.f;
    if (tid < 99) {
        int i = tid;
        float tot = 0.f; int cv = 0;
        for (int b = 0; b < BB; b++) {
            tot += nll[b * 99 + i];
            cv += (head[b * SS + i + 1] != -1) ? 1 : 0;
        }
        int denom = cv > 0 ? cv : 1;
        contrib = tot / (float)denom;
    }
    red[tid] = contrib;
    __syncthreads();
    for (int off = 64; off >= 1; off >>= 1) {
        if (tid < off) red[tid] += red[tid + off];
        __syncthreads();
    }
    if (tid == 0) outb[0] = red[0];
}

// ---------------- launch (7 nodes) ----------------
extern "C" void kernel_launch(void* const* d_in, const int* in_sizes, int n_in,
                              void* d_out, int out_size, void* d_ws, size_t ws_size,
                              hipStream_t stream) {
    const int*   tok     = (const int*)d_in[0];
    const int*   pos     = (const int*)d_in[1];
    const int*   head    = (const int*)d_in[2];
    const float* word_W  = (const float*)d_in[3];
    const float* pos_W   = (const float*)d_in[4];
    const float* l0f_Wih = (const float*)d_in[5];
    const float* l0f_Whh = (const float*)d_in[6];
    const float* l0f_b   = (const float*)d_in[7];
    const float* l0b_Wih = (const float*)d_in[8];
    const float* l0b_Whh = (const float*)d_in[9];
    const float* l0b_b   = (const float*)d_in[10];
    const float* l1f_Wih = (const float*)d_in[11];
    const float* l1f_Whh = (const float*)d_in[12];
    const float* l1f_b   = (const float*)d_in[13];
    const float* l1b_Wih = (const float*)d_in[14];
    const float* l1b_Whh = (const float*)d_in[15];
    const float* l1b_b   = (const float*)d_in[16];
    const float* ua_W    = (const float*)d_in[17];
    const float* ua_b    = (const float*)d_in[18];
    const float* wa_W    = (const float*)d_in[19];
    const float* wa_b    = (const float*)d_in[20];
    const float* va_W    = (const float*)d_in[21];

    float* ws   = (float*)d_ws;
    float* gf   = ws + OFF_GF;   // g0f / g1f / ua
    float* gb   = ws + OFF_GB;   // g0b / g1b / wa
    float* h1   = ws + OFF_H1;
    float* out2 = ws + OFF_OUT2;
    float* nllb = ws + OFF_NLL;
    unsigned short* exhi = (unsigned short*)(ws + OFF_EXH);
    unsigned short* exlo = exhi + EX_U16_PER_PLANE;
    float* outf = (float*)d_out;

    // layer-0 projections: fused embedding + LDS-staged A + poison init
    gemm_l0_embed_dual<<<dim3(50, 25), 256, 0, stream>>>(
        tok, pos, word_W, pos_W,
        l0f_Wih, l0f_b, gf, l0b_Wih, l0b_b, gb,
        (unsigned int*)exhi, (int)EX_U16_PER_PLANE);
    // layer-0 recurrence
    lstm_layer_kernel<<<dim3(200), 64, 0, stream>>>(
        gf, gb, l0f_Whh, l0b_Whh, h1, exhi, exlo);
    // layer-1 projections (K=800) + exchange re-poison
    gemm_nt_mfma_dual<<<dim3(50, 25), 256, 0, stream>>>(
        h1, l1f_Wih, l1f_b, gf, l1b_Wih, l1b_b, gb, H2, G4,
        (unsigned int*)exhi, (int)EX_U16_PER_PLANE);
    // layer-1 recurrence
    lstm_layer_kernel<<<dim3(200), 64, 0, stream>>>(
        gf, gb, l1f_Whh, l1b_Whh, out2, exhi, exlo);
    // attention projections (K=800, R=800)
    gemm_nt_mfma_dual<<<dim3(26, 25), 256, 0, stream>>>(
        out2, ua_W, ua_b, gf, wa_W, wa_b, gb, H2, H2, nullptr, 0);
    // scores + fused softmax/table/preds/nll
    attn_scores_softmax_kernel<<<dim3(16 * 9), 256, 0, stream>>>(
        gf, gb, va_W, out2, head, outf, nllb);
    // final loss
    loss_kernel<<<dim3(1), 128, 0, stream>>>(nllb, head, outf);
}